// Round 8
// baseline (872.641 us; speedup 1.0000x reference)
//
#include <hip/hip_runtime.h>
#include <math.h>

#define PP 384
#define HH 768
#define KK 4
#define BB 16
#define LL 2048
#define MM (BB*LL)   // 32768
#define NCH (BB*PP)  // 6144
#define NC 32
#define CLEN (LL/NC) // 64

typedef __attribute__((ext_vector_type(8))) short bf16x8;
typedef __attribute__((ext_vector_type(4))) float f32x4;

__device__ __forceinline__ float sigmoid_fast(float x) { return 1.0f / (1.0f + __expf(-x)); }

__device__ __forceinline__ float bf2f(unsigned short h) {
    return __uint_as_float(((unsigned int)h) << 16);
}
__device__ __forceinline__ unsigned short f2bf(float x) {
    unsigned int u = __float_as_uint(x);
    u += 0x7fff + ((u >> 16) & 1);          // round-to-nearest-even
    return (unsigned short)(u >> 16);
}
// split x into hi (bf16) and lo (bf16 of residual): x ≈ hi + lo, err ~2^-17
__device__ __forceinline__ void split_bf(float x, unsigned short& hi, unsigned short& lo) {
    hi = f2bf(x);
    lo = f2bf(x - bf2f(hi));
}

__device__ __forceinline__ void gll16(const void* g, void* l) {
    __builtin_amdgcn_global_load_lds(
        (const __attribute__((address_space(1))) void*)g,
        (__attribute__((address_space(3))) void*)l, 16, 0, 0);
}

// Bijective XCD-aware block swizzle (m204).
__device__ __forceinline__ void xcd_swizzle(int& bx, int& by) {
    const int gx = (int)gridDim.x;
    const int nwg = gx * (int)gridDim.y;
    const int orig = by * gx + bx;
    const int q = nwg >> 3, r = nwg & 7;
    const int xcd = orig & 7, off = orig >> 3;
    const int swz = (xcd < r ? xcd * (q + 1) : r * (q + 1) + (xcd - r) * q) + off;
    bx = swz % gx;
    by = swz / gx;
}

// Per-step scalar coefficients (state-independent), fast-math, used
// identically in compose and apply phases.
__device__ __forceinline__ void step_coef(float Rp, float Tp, float Ip,
    float rb, float tb, float il, float dt,
    float& c0, float& c1, float& gdt)
{
    const float PIf = 3.14159265358979323846f;
    float r  = sigmoid_fast(rb + Rp);
    float t  = tb + Tp;
    float e2 = __expf(2.0f * fabsf(t));
    float th = PIf * copysignf(1.0f - 2.0f / (e2 + 1.0f), t);
    float ct = __cosf(th);
    float r2 = fmaxf(r * r, 1e-8f);
    float Ac = (r2 - 2.0f * r * ct + 1.0f) / (dt * dt * r2);
    float Gc = (1.0f - r2) / (dt * r2);
    float S  = 1.0f / (1.0f + dt * Gc);
    float gate = sigmoid_fast(il + Ip);
    c0 = S;
    c1 = S * (dt * Ac);
    gdt = S * dt * gate;
}

// ---------------------------------------------------------------------------
// Weight repack (interleaved layouts for scan-friendly reads):
//  wlh/wll (768x768)       = Wl split hi/lo
//  wrth h/l (768x768)      : row 2p=Wr[p], row 2p+1=Wth[p]  (split hi/lo)
//  winj (384x768) bf16     = Winj
//  wb (768x768) bf16       : row 2p=BRe[p], row 2p+1=BIm[p]
//  wc (768x768) bf16       : wc[i] = (i&1) ? -CIm : CRe  (natural Cp order)
// ---------------------------------------------------------------------------
__global__ __launch_bounds__(256) void repack_kernel(
    const float* __restrict__ Wl, const float* __restrict__ Wr,
    const float* __restrict__ Wth, const float* __restrict__ Winj,
    const float* __restrict__ Bp, const float* __restrict__ Cp,
    unsigned short* __restrict__ wlh, unsigned short* __restrict__ wll,
    unsigned short* __restrict__ wrth_h, unsigned short* __restrict__ wrth_l,
    unsigned short* __restrict__ winj,
    unsigned short* __restrict__ wb, unsigned short* __restrict__ wc)
{
    int i = blockIdx.x * 256 + threadIdx.x;
    const int NB = 768 * 768, NI = 384 * 768;
    if (i < NB) { split_bf(Wl[i], wlh[i], wll[i]); return; }
    i -= NB;
    if (i < NB) {    // interleaved [Wr;Wth]
        int n = i / 768, k = i - n * 768;
        int p = n >> 1;
        float v = (n & 1) ? Wth[p * 768 + k] : Wr[p * 768 + k];
        split_bf(v, wrth_h[i], wrth_l[i]);
        return;
    }
    i -= NB;
    if (i < NI) { winj[i] = f2bf(Winj[i]); return; }
    i -= NI;
    if (i < NB) {    // interleaved [BRe;BIm]
        int n = i / 768, k = i - n * 768;
        wb[i] = f2bf(Bp[(size_t)(n >> 1) * 1536 + k * 2 + (n & 1)]);
        return;
    }
    i -= NB;
    if (i < NB) {    // col-interleaved [CRe|-CIm] == sign-flipped natural Cp
        wc[i] = f2bf((i & 1) ? -Cp[i] : Cp[i]);
    }
}

// inputs -> hi/lo split buffers
__global__ __launch_bounds__(256) void split_convert_kernel(
    const float* __restrict__ in, unsigned short* __restrict__ outh,
    unsigned short* __restrict__ outl, int n4)
{
    int i = blockIdx.x * 256 + threadIdx.x;
    if (i >= n4) return;
    float4 a = ((const float4*)in)[i];
    ushort4 h, l;
    split_bf(a.x, h.x, l.x); split_bf(a.y, h.y, l.y);
    split_bf(a.z, h.z, l.z); split_bf(a.w, h.w, l.w);
    ((ushort4*)outh)[i] = h;
    ((ushort4*)outl)[i] = l;
}

// ---------------------------------------------------------------------------
// FUSED split+plain MFMA GEMM. Columns [0,768): split-precision (3 MFMA,
// Ah/Al x Wsh/Wsl) -> fp32 outS. Columns [768, 768+NPLAIN): plain bf16
// (Ah x Wp) -> bf16 outP.
// KIND 0 (encoder+bu): NPLAIN=768, split epilogue = silu(x+bias), outP stride 768
// KIND 1 (heads+inj):  NPLAIN=384, split epilogue = raw,          outP stride 384
// grid = ((768+NPLAIN)/128, M/128), XCD-swizzled.
// ---------------------------------------------------------------------------
template <int KIND>
__global__ __launch_bounds__(256) void mfma_gemm_fused(
    const unsigned short* __restrict__ Ah, const unsigned short* __restrict__ Al,
    const unsigned short* __restrict__ Wsh, const unsigned short* __restrict__ Wsl,
    const unsigned short* __restrict__ Wp,
    float* __restrict__ outS, unsigned short* __restrict__ outP,
    const float* __restrict__ bias)
{
    constexpr int K = 768;
    constexpr int NSPLIT = 768;
    constexpr int STRIDE_P = (KIND == 0) ? 768 : 384;
    __shared__ unsigned short lsAh[128 * 32];
    __shared__ unsigned short lsAl[128 * 32];
    __shared__ unsigned short lsBh[128 * 32];
    __shared__ unsigned short lsBl[128 * 32];
    const int tid  = threadIdx.x;
    const int wave = tid >> 6, lane = tid & 63;
    const int wm = wave >> 1, wn = wave & 1;
    int bx = blockIdx.x, by = blockIdx.y;
    xcd_swizzle(bx, by);
    const int row0 = by * 128, col0 = bx * 128;
    const bool is_split = (col0 < NSPLIT);
    const int bcol0 = is_split ? col0 : col0 - NSPLIT;

    const int srow = (wave << 4) + (lane >> 2);    // 0..63
    const int scol = (lane & 3) << 3;              // 0,8,16,24
    const size_t ga0 = (size_t)(row0 + srow) * K + scol;
    const size_t ga1 = (size_t)(row0 + 64 + srow) * K + scol;
    const size_t gb0 = (size_t)(bcol0 + srow) * K + scol;
    const size_t gb1 = (size_t)(bcol0 + 64 + srow) * K + scol;
    const int l0 = srow * 32 + scol;
    const int l1 = (64 + srow) * 32 + scol;
    const unsigned short* Bh_src = is_split ? Wsh : Wp;

    f32x4 acc[4][4];
#pragma unroll
    for (int i = 0; i < 4; ++i)
#pragma unroll
        for (int j = 0; j < 4; ++j) acc[i][j] = (f32x4){0.f, 0.f, 0.f, 0.f};

    const int rfo = ((lane & 15) * 32) + ((lane >> 4) << 3);

    for (int kt = 0; kt < K; kt += 32) {
        __syncthreads();
        gll16(Ah + ga0 + kt, &lsAh[l0]);
        gll16(Ah + ga1 + kt, &lsAh[l1]);
        gll16(Bh_src + gb0 + kt, &lsBh[l0]);
        gll16(Bh_src + gb1 + kt, &lsBh[l1]);
        if (is_split) {
            gll16(Al + ga0 + kt, &lsAl[l0]);
            gll16(Al + ga1 + kt, &lsAl[l1]);
            gll16(Wsl + gb0 + kt, &lsBl[l0]);
            gll16(Wsl + gb1 + kt, &lsBl[l1]);
        }
        __syncthreads();
        bf16x8 afh[4], bfh[4];
#pragma unroll
        for (int i = 0; i < 4; ++i)
            afh[i] = *(const bf16x8*)&lsAh[(wm * 64 + i * 16) * 32 + rfo];
#pragma unroll
        for (int j = 0; j < 4; ++j)
            bfh[j] = *(const bf16x8*)&lsBh[(wn * 64 + j * 16) * 32 + rfo];
        if (is_split) {
            bf16x8 afl[4], bfl[4];
#pragma unroll
            for (int i = 0; i < 4; ++i)
                afl[i] = *(const bf16x8*)&lsAl[(wm * 64 + i * 16) * 32 + rfo];
#pragma unroll
            for (int j = 0; j < 4; ++j)
                bfl[j] = *(const bf16x8*)&lsBl[(wn * 64 + j * 16) * 32 + rfo];
#pragma unroll
            for (int i = 0; i < 4; ++i)
#pragma unroll
                for (int j = 0; j < 4; ++j) {
                    acc[i][j] = __builtin_amdgcn_mfma_f32_16x16x32_bf16(afh[i], bfh[j], acc[i][j], 0, 0, 0);
                    acc[i][j] = __builtin_amdgcn_mfma_f32_16x16x32_bf16(afh[i], bfl[j], acc[i][j], 0, 0, 0);
                    acc[i][j] = __builtin_amdgcn_mfma_f32_16x16x32_bf16(afl[i], bfh[j], acc[i][j], 0, 0, 0);
                }
        } else {
#pragma unroll
            for (int i = 0; i < 4; ++i)
#pragma unroll
                for (int j = 0; j < 4; ++j)
                    acc[i][j] = __builtin_amdgcn_mfma_f32_16x16x32_bf16(afh[i], bfh[j], acc[i][j], 0, 0, 0);
        }
    }

    const int rbase = row0 + wm * 64 + ((lane >> 4) << 2);
    const int cbase = col0 + wn * 64 + (lane & 15);
#pragma unroll
    for (int i = 0; i < 4; ++i) {
#pragma unroll
        for (int j = 0; j < 4; ++j) {
            const int cg = cbase + j * 16;
            float bv = (KIND == 0 && bias) ? bias[cg < NSPLIT ? cg : 0] : 0.f;
#pragma unroll
            for (int q = 0; q < 4; ++q) {
                const int rg = rbase + i * 16 + q;
                float v = acc[i][j][q];
                if (is_split) {
                    const size_t off = (size_t)rg * 768 + cg;
                    if (KIND == 0) {
                        float x = v + bv;
                        outS[off] = x * sigmoid_fast(x);
                    } else {
                        outS[off] = v;
                    }
                } else {
                    const size_t off = (size_t)rg * STRIDE_P + (cg - NSPLIT);
                    outP[off] = f2bf(v);
                }
            }
        }
    }
}

// ---------------------------------------------------------------------------
// plain bf16 MFMA GEMM, MODE 2 epilogue: out = acc + bf2f(resid)*Dv, fp32.
// grid = (N/128, M/128), XCD-swizzled.
// ---------------------------------------------------------------------------
__global__ __launch_bounds__(256) void mfma_gemm_out(
    const unsigned short* __restrict__ A, const unsigned short* __restrict__ W,
    float* __restrict__ Cout, int N,
    const unsigned short* __restrict__ resid, const float* __restrict__ Dv)
{
    constexpr int K = 768;
    __shared__ unsigned short lsA[128 * 32];
    __shared__ unsigned short lsB[128 * 32];
    const int tid  = threadIdx.x;
    const int wave = tid >> 6, lane = tid & 63;
    const int wm = wave >> 1, wn = wave & 1;
    int bx = blockIdx.x, by = blockIdx.y;
    xcd_swizzle(bx, by);
    const int row0 = by * 128, col0 = bx * 128;

    const int srow = (wave << 4) + (lane >> 2);
    const int scol = (lane & 3) << 3;
    const size_t ga0 = (size_t)(row0 + srow) * K + scol;
    const size_t ga1 = (size_t)(row0 + 64 + srow) * K + scol;
    const size_t gb0 = (size_t)(col0 + srow) * K + scol;
    const size_t gb1 = (size_t)(col0 + 64 + srow) * K + scol;
    const int l0 = srow * 32 + scol;
    const int l1 = (64 + srow) * 32 + scol;

    f32x4 acc[4][4];
#pragma unroll
    for (int i = 0; i < 4; ++i)
#pragma unroll
        for (int j = 0; j < 4; ++j) acc[i][j] = (f32x4){0.f, 0.f, 0.f, 0.f};

    const int rfo = ((lane & 15) * 32) + ((lane >> 4) << 3);

    for (int kt = 0; kt < K; kt += 32) {
        __syncthreads();
        gll16(A + ga0 + kt, &lsA[l0]);
        gll16(A + ga1 + kt, &lsA[l1]);
        gll16(W + gb0 + kt, &lsB[l0]);
        gll16(W + gb1 + kt, &lsB[l1]);
        __syncthreads();
        bf16x8 af[4], bfg[4];
#pragma unroll
        for (int i = 0; i < 4; ++i)
            af[i] = *(const bf16x8*)&lsA[(wm * 64 + i * 16) * 32 + rfo];
#pragma unroll
        for (int j = 0; j < 4; ++j)
            bfg[j] = *(const bf16x8*)&lsB[(wn * 64 + j * 16) * 32 + rfo];
#pragma unroll
        for (int i = 0; i < 4; ++i)
#pragma unroll
            for (int j = 0; j < 4; ++j)
                acc[i][j] = __builtin_amdgcn_mfma_f32_16x16x32_bf16(af[i], bfg[j], acc[i][j], 0, 0, 0);
    }

    const int rbase = row0 + wm * 64 + ((lane >> 4) << 2);
    const int cbase = col0 + wn * 64 + (lane & 15);
#pragma unroll
    for (int i = 0; i < 4; ++i) {
#pragma unroll
        for (int j = 0; j < 4; ++j) {
            const int cg = cbase + j * 16;
            const float dv = Dv[cg];
#pragma unroll
            for (int q = 0; q < 4; ++q) {
                const int rg = rbase + i * 16 + q;
                const size_t off = (size_t)rg * N + cg;
                Cout[off] = acc[i][j][q] + bf2f(resid[off]) * dv;
            }
        }
    }
}

// ---------------------------------------------------------------------------
// Causal depthwise conv (K=4) + bias + silu. fp32 in, hi/lo bf16 out.
// 4 h-channels per thread (float4 / ushort4).
// ---------------------------------------------------------------------------
__global__ __launch_bounds__(256) void conv_silu_kernel(
    const float* __restrict__ x, const float* __restrict__ w,
    const float* __restrict__ cb, unsigned short* __restrict__ yh,
    unsigned short* __restrict__ yl)
{
    int i4 = blockIdx.x * 256 + threadIdx.x;       // over MM*HH/4
    if (i4 >= MM * HH / 4) return;
    const int HQ = HH / 4;                          // 192
    int h4 = (i4 % HQ) * 4;
    int ml = i4 / HQ;
    int l  = ml % LL;
    float a0 = cb[h4], a1 = cb[h4 + 1], a2 = cb[h4 + 2], a3 = cb[h4 + 3];
#pragma unroll
    for (int j = 0; j < KK; ++j) {
        int d = (KK - 1) - j;
        if (l - d >= 0) {
            float4 xv = *(const float4*)(x + (size_t)(ml - d) * HH + h4);
            a0 = fmaf(xv.x, w[(h4 + 0) * KK + j], a0);
            a1 = fmaf(xv.y, w[(h4 + 1) * KK + j], a1);
            a2 = fmaf(xv.z, w[(h4 + 2) * KK + j], a2);
            a3 = fmaf(xv.w, w[(h4 + 3) * KK + j], a3);
        }
    }
    float y0 = a0 * sigmoid_fast(a0);
    float y1 = a1 * sigmoid_fast(a1);
    float y2 = a2 * sigmoid_fast(a2);
    float y3 = a3 * sigmoid_fast(a3);
    ushort4 vh, vl;
    split_bf(y0, vh.x, vl.x); split_bf(y1, vh.y, vl.y);
    split_bf(y2, vh.z, vl.z); split_bf(y3, vh.w, vl.w);
    *(ushort4*)(yh + (size_t)i4 * 4) = vh;
    *(ushort4*)(yl + (size_t)i4 * 4) = vl;
}

// ---------------------------------------------------------------------------
// Chunked scan with interleaved layouts:
//  heads_rt (M,768) fp32: [2p]=Rpre, [2p+1]=Thpre
//  heads_inj (M,384) bf16; bu (M,768) bf16: [2p]=Re, [2p+1]=Im
//  states (M,768) bf16 out: [2p]=xRe, [2p+1]=xIm
// ---------------------------------------------------------------------------
__global__ __launch_bounds__(256) void scan_chunk_kernel(
    const float* __restrict__ heads_rt, const unsigned short* __restrict__ heads_inj,
    const unsigned short* __restrict__ bu,
    const float* __restrict__ r_base, const float* __restrict__ th_base,
    const float* __restrict__ dt_base, const float* __restrict__ inj,
    float4* __restrict__ summA, float4* __restrict__ summB)
{
    int g = blockIdx.x * 256 + threadIdx.x;
    if (g >= NC * NCH) return;
    int t = g % NCH;
    int j = g / NCH;
    int b = t / PP, p = t - b * PP;
    const float rb = r_base[p], tb = th_base[p], il = inj[p];
    const float dt = 0.02f + 0.98f * sigmoid_fast(dt_base[p]);
    float m00 = 1.f, m01 = 0.f, m10 = 0.f, m11 = 1.f;
    float vzR = 0.f, vxR = 0.f, vzI = 0.f, vxI = 0.f;
    const int mbase = b * LL + j * CLEN;
    for (int l = 0; l < CLEN; ++l) {
        const size_t m = (size_t)(mbase + l);
        const float2 rt = *(const float2*)(heads_rt + m * 768 + 2 * p);
        const float Ip = bf2f(heads_inj[m * 384 + p]);
        const ushort2 bv = *(const ushort2*)(bu + m * 768 + 2 * p);
        const float b0 = bf2f(bv.x), b1 = bf2f(bv.y);
        float c0, c1, gdt;
        step_coef(rt.x, rt.y, Ip, rb, tb, il, dt, c0, c1, gdt);
        const float azR = gdt * b0, azI = gdt * b1;
        float nm00 = c0 * m00 - c1 * m10;
        float nm01 = c0 * m01 - c1 * m11;
        m10 = fmaf(dt, nm00, m10);
        m11 = fmaf(dt, nm01, m11);
        m00 = nm00; m01 = nm01;
        float nvzR = c0 * vzR - c1 * vxR + azR;
        vxR = fmaf(dt, nvzR, vxR); vzR = nvzR;
        float nvzI = c0 * vzI - c1 * vxI + azI;
        vxI = fmaf(dt, nvzI, vxI); vzI = nvzI;
    }
    summA[g] = make_float4(m00, m01, m10, m11);
    summB[g] = make_float4(vzR, vxR, vzI, vxI);
}

__global__ __launch_bounds__(256) void scan_mid_kernel(
    const float4* __restrict__ summA, const float4* __restrict__ summB,
    float4* __restrict__ starts)
{
    int t = blockIdx.x * 256 + threadIdx.x;
    if (t >= NCH) return;
    float zR = 0.f, xR = 0.f, zI = 0.f, xI = 0.f;
    for (int j = 0; j < NC; ++j) {
        starts[j * NCH + t] = make_float4(zR, xR, zI, xI);
        float4 Mv = summA[j * NCH + t];
        float4 Vv = summB[j * NCH + t];
        float nzR = Mv.x * zR + Mv.y * xR + Vv.x;
        float nxR = Mv.z * zR + Mv.w * xR + Vv.y;
        float nzI = Mv.x * zI + Mv.y * xI + Vv.z;
        float nxI = Mv.z * zI + Mv.w * xI + Vv.w;
        zR = nzR; xR = nxR; zI = nzI; xI = nxI;
    }
}

__global__ __launch_bounds__(256) void scan_apply_kernel(
    const float* __restrict__ heads_rt, const unsigned short* __restrict__ heads_inj,
    const unsigned short* __restrict__ bu,
    const float* __restrict__ r_base, const float* __restrict__ th_base,
    const float* __restrict__ dt_base, const float* __restrict__ inj,
    const float4* __restrict__ starts, unsigned short* __restrict__ states)
{
    int g = blockIdx.x * 256 + threadIdx.x;
    if (g >= NC * NCH) return;
    int t = g % NCH;
    int j = g / NCH;
    int b = t / PP, p = t - b * PP;
    const float rb = r_base[p], tb = th_base[p], il = inj[p];
    const float dt = 0.02f + 0.98f * sigmoid_fast(dt_base[p]);
    float4 s0 = starts[j * NCH + t];
    float zR = s0.x, xR = s0.y, zI = s0.z, xI = s0.w;
    const int mbase = b * LL + j * CLEN;
    for (int l = 0; l < CLEN; ++l) {
        const size_t m = (size_t)(mbase + l);
        const float2 rt = *(const float2*)(heads_rt + m * 768 + 2 * p);
        const float Ip = bf2f(heads_inj[m * 384 + p]);
        const ushort2 bv = *(const ushort2*)(bu + m * 768 + 2 * p);
        const float b0 = bf2f(bv.x), b1 = bf2f(bv.y);
        float c0, c1, gdt;
        step_coef(rt.x, rt.y, Ip, rb, tb, il, dt, c0, c1, gdt);
        zR = c0 * zR - c1 * xR + gdt * b0;
        xR = fmaf(dt, zR, xR);
        zI = c0 * zI - c1 * xI + gdt * b1;
        xI = fmaf(dt, zI, xI);
        ushort2 sv;
        sv.x = f2bf(xR);
        sv.y = f2bf(xI);
        *(ushort2*)(states + m * 768 + 2 * p) = sv;
    }
}

// ---------------------------------------------------------------------------
extern "C" void kernel_launch(void* const* d_in, const int* in_sizes, int n_in,
                              void* d_out, int out_size, void* d_ws, size_t ws_size,
                              hipStream_t stream)
{
    const float* inputs  = (const float*)d_in[0];
    const float* Wl      = (const float*)d_in[1];
    const float* bl      = (const float*)d_in[2];
    const float* conv_w  = (const float*)d_in[3];
    const float* conv_b  = (const float*)d_in[4];
    const float* Wr      = (const float*)d_in[5];
    const float* Wth     = (const float*)d_in[6];
    const float* Winj    = (const float*)d_in[7];
    const float* r_base  = (const float*)d_in[8];
    const float* th_base = (const float*)d_in[9];
    const float* dt_base = (const float*)d_in[10];
    const float* inj_l   = (const float*)d_in[11];
    const float* Bp      = (const float*)d_in[12];
    const float* Cp      = (const float*)d_in[13];
    const float* Dv      = (const float*)d_in[14];
    float* out = (float*)d_out;

    // ---- workspace layout (lifetime-aliased) ----
    const size_t NB = 768 * 768, NI = 384 * 768, NMH = (size_t)MM * 768;
    unsigned short* wlh    = (unsigned short*)d_ws;
    unsigned short* wll    = wlh + NB;
    unsigned short* wrth_h = wll + NB;
    unsigned short* wrth_l = wrth_h + NB;
    unsigned short* winj   = wrth_l + NB;
    unsigned short* wb     = winj + NI;
    unsigned short* wc     = wb + NB;
    unsigned short* inh    = wc + NB;            // MM*768 bf16, live t3..t9
    unsigned short* inl    = inh + NMH;          // live t3 only -> states later
    unsigned short* f2h    = inl + NMH;          // conv out hi, live t4..t5
    unsigned short* f2l    = f2h + NMH;          // conv out lo
    unsigned short* hinj   = f2l + NMH;          // heads_inj bf16 MM*384
    float* f1       = (float*)(hinj + (size_t)MM * 384);   // enc out fp32 (96MB)
    float* heads_rt = f1;                        // overlays f1 (dead after conv)
    float4* summA = (float4*)(f1 + NMH);
    float4* summB = summA + (size_t)NC * NCH;
    float4* starts= summB + (size_t)NC * NCH;
    unsigned short* bu = (unsigned short*)d_out; // bf16 MM*768, dead after scan
    unsigned short* states = inl;                // overlays dead inl

    // t1. repack weights ; t2. split-convert inputs
    {
        int total = (int)(4 * NB + NI);
        repack_kernel<<<(total + 255) / 256, 256, 0, stream>>>(
            Wl, Wr, Wth, Winj, Bp, Cp, wlh, wll, wrth_h, wrth_l, winj, wb, wc);
        int n4 = (int)(NMH / 4);
        split_convert_kernel<<<(n4 + 255) / 256, 256, 0, stream>>>(inputs, inh, inl, n4);
    }
    // t3. fused encoder(split, silu->f1) + bu(plain, bf16->d_out)
    mfma_gemm_fused<0><<<dim3(12, MM / 128), 256, 0, stream>>>(
        inh, inl, wlh, wll, wb, f1, bu, bl);
    // t4. conv + silu: f1 -> f2 hi/lo
    conv_silu_kernel<<<(MM * HH / 4 + 255) / 256, 256, 0, stream>>>(f1, conv_w, conv_b, f2h, f2l);
    // t5. fused heads(split, raw->heads_rt) + inj(plain, bf16->hinj)
    mfma_gemm_fused<1><<<dim3(9, MM / 128), 256, 0, stream>>>(
        f2h, f2l, wrth_h, wrth_l, winj, heads_rt, hinj, nullptr);
    // t6-t8. chunked scan
    scan_chunk_kernel<<<(NC * NCH) / 256, 256, 0, stream>>>(
        heads_rt, hinj, bu, r_base, th_base, dt_base, inj_l, summA, summB);
    scan_mid_kernel<<<(NCH + 255) / 256, 256, 0, stream>>>(summA, summB, starts);
    scan_apply_kernel<<<(NC * NCH) / 256, 256, 0, stream>>>(
        heads_rt, hinj, bu, r_base, th_base, dt_base, inj_l, starts, states);
    // t9. output projection + residual (resid read as bf16 inh)
    mfma_gemm_out<<<dim3(6, MM / 128), 256, 0, stream>>>(
        states, wc, out, 768, inh, Dv);
}

// Round 9
// 772.994 us; speedup vs baseline: 1.1289x; 1.1289x over previous
//
#include <hip/hip_runtime.h>
#include <math.h>

#define PP 384
#define HH 768
#define KK 4
#define BB 16
#define LL 2048
#define MM (BB*LL)   // 32768
#define NCH (BB*PP)  // 6144
#define NC 32
#define CLEN (LL/NC) // 64

typedef __attribute__((ext_vector_type(8))) short bf16x8;
typedef __attribute__((ext_vector_type(4))) float f32x4;

__device__ __forceinline__ float sigmoid_fast(float x) { return 1.0f / (1.0f + __expf(-x)); }

__device__ __forceinline__ float bf2f(unsigned short h) {
    return __uint_as_float(((unsigned int)h) << 16);
}
__device__ __forceinline__ unsigned short f2bf(float x) {
    unsigned int u = __float_as_uint(x);
    u += 0x7fff + ((u >> 16) & 1);          // round-to-nearest-even
    return (unsigned short)(u >> 16);
}
// split x into hi (bf16) and lo (bf16 of residual): x ≈ hi + lo, err ~2^-17
__device__ __forceinline__ void split_bf(float x, unsigned short& hi, unsigned short& lo) {
    hi = f2bf(x);
    lo = f2bf(x - bf2f(hi));
}

__device__ __forceinline__ void gll16(const void* g, void* l) {
    __builtin_amdgcn_global_load_lds(
        (const __attribute__((address_space(1))) void*)g,
        (__attribute__((address_space(3))) void*)l, 16, 0, 0);
}

// Bijective XCD-aware block swizzle (m204): each XCD owns consecutive work
// units -> A row-panels fetched once chip-wide, W resident in per-XCD L2.
__device__ __forceinline__ void xcd_swizzle(int& bx, int& by) {
    const int gx = (int)gridDim.x;
    const int nwg = gx * (int)gridDim.y;
    const int orig = by * gx + bx;
    const int q = nwg >> 3, r = nwg & 7;
    const int xcd = orig & 7, off = orig >> 3;
    const int swz = (xcd < r ? xcd * (q + 1) : r * (q + 1) + (xcd - r) * q) + off;
    bx = swz % gx;
    by = swz / gx;
}

// Per-step scalar coefficients (state-independent), fast-math, used
// identically in compose and apply phases.
__device__ __forceinline__ void step_coef(float Rp, float Tp, float Ip,
    float rb, float tb, float il, float dt,
    float& c0, float& c1, float& gdt)
{
    const float PIf = 3.14159265358979323846f;
    float r  = sigmoid_fast(rb + Rp);
    float t  = tb + Tp;
    float e2 = __expf(2.0f * fabsf(t));
    float th = PIf * copysignf(1.0f - 2.0f / (e2 + 1.0f), t);
    float ct = __cosf(th);
    float r2 = fmaxf(r * r, 1e-8f);
    float Ac = (r2 - 2.0f * r * ct + 1.0f) / (dt * dt * r2);
    float Gc = (1.0f - r2) / (dt * r2);
    float S  = 1.0f / (1.0f + dt * Gc);
    float gate = sigmoid_fast(il + Ip);
    c0 = S;
    c1 = S * (dt * Ac);
    gdt = S * dt * gate;
}

// ---------------------------------------------------------------------------
// Weight repack (interleaved layouts for scan-friendly reads):
//  wlh/wll (768x768)       = Wl split hi/lo
//  wrth h/l (768x768)      : row 2p=Wr[p], row 2p+1=Wth[p]  (split hi/lo)
//  winj (384x768) bf16     = Winj
//  wb (768x768) bf16       : row 2p=BRe[p], row 2p+1=BIm[p]
//  wc (768x768) bf16       : wc[i] = (i&1) ? -CIm : CRe  (natural Cp order)
// ---------------------------------------------------------------------------
__global__ __launch_bounds__(256) void repack_kernel(
    const float* __restrict__ Wl, const float* __restrict__ Wr,
    const float* __restrict__ Wth, const float* __restrict__ Winj,
    const float* __restrict__ Bp, const float* __restrict__ Cp,
    unsigned short* __restrict__ wlh, unsigned short* __restrict__ wll,
    unsigned short* __restrict__ wrth_h, unsigned short* __restrict__ wrth_l,
    unsigned short* __restrict__ winj,
    unsigned short* __restrict__ wb, unsigned short* __restrict__ wc)
{
    int i = blockIdx.x * 256 + threadIdx.x;
    const int NB = 768 * 768, NI = 384 * 768;
    if (i < NB) { split_bf(Wl[i], wlh[i], wll[i]); return; }
    i -= NB;
    if (i < NB) {    // interleaved [Wr;Wth]
        int n = i / 768, k = i - n * 768;
        int p = n >> 1;
        float v = (n & 1) ? Wth[p * 768 + k] : Wr[p * 768 + k];
        split_bf(v, wrth_h[i], wrth_l[i]);
        return;
    }
    i -= NB;
    if (i < NI) { winj[i] = f2bf(Winj[i]); return; }
    i -= NI;
    if (i < NB) {    // interleaved [BRe;BIm]
        int n = i / 768, k = i - n * 768;
        wb[i] = f2bf(Bp[(size_t)(n >> 1) * 1536 + k * 2 + (n & 1)]);
        return;
    }
    i -= NB;
    if (i < NB) {    // col-interleaved [CRe|-CIm] == sign-flipped natural Cp
        wc[i] = f2bf((i & 1) ? -Cp[i] : Cp[i]);
    }
}

// inputs -> hi/lo split buffers
__global__ __launch_bounds__(256) void split_convert_kernel(
    const float* __restrict__ in, unsigned short* __restrict__ outh,
    unsigned short* __restrict__ outl, int n4)
{
    int i = blockIdx.x * 256 + threadIdx.x;
    if (i >= n4) return;
    float4 a = ((const float4*)in)[i];
    ushort4 h, l;
    split_bf(a.x, h.x, l.x); split_bf(a.y, h.y, l.y);
    split_bf(a.z, h.z, l.z); split_bf(a.w, h.w, l.w);
    ((ushort4*)outh)[i] = h;
    ((ushort4*)outl)[i] = l;
}

// ---------------------------------------------------------------------------
// SPLIT-PRECISION bf16 MFMA GEMM: C = (Ah+Al) @ (Wh+Wl)^T  (3 MFMAs/k-step)
// grid = (N/128, M/128), XCD-swizzled.
// SMODE 0: fp32 out. SMODE 1: +bias, silu, fp32 out.
// ---------------------------------------------------------------------------
template <int SMODE>
__global__ __launch_bounds__(256) void mfma_gemm_split(
    const unsigned short* __restrict__ Ah, const unsigned short* __restrict__ Al,
    const unsigned short* __restrict__ Wh, const unsigned short* __restrict__ Wl,
    float* __restrict__ Cout, int N, const float* __restrict__ bias)
{
    constexpr int K = 768;
    __shared__ unsigned short lsAh[128 * 32];
    __shared__ unsigned short lsAl[128 * 32];
    __shared__ unsigned short lsBh[128 * 32];
    __shared__ unsigned short lsBl[128 * 32];
    const int tid  = threadIdx.x;
    const int wave = tid >> 6, lane = tid & 63;
    const int wm = wave >> 1, wn = wave & 1;
    int bx = blockIdx.x, by = blockIdx.y;
    xcd_swizzle(bx, by);
    const int row0 = by * 128, col0 = bx * 128;

    const int srow = (wave << 4) + (lane >> 2);    // 0..63
    const int scol = (lane & 3) << 3;              // 0,8,16,24
    const size_t ga0 = (size_t)(row0 + srow) * K + scol;
    const size_t ga1 = (size_t)(row0 + 64 + srow) * K + scol;
    const size_t gb0 = (size_t)(col0 + srow) * K + scol;
    const size_t gb1 = (size_t)(col0 + 64 + srow) * K + scol;
    const int l0 = srow * 32 + scol;
    const int l1 = (64 + srow) * 32 + scol;

    f32x4 acc[4][4];
#pragma unroll
    for (int i = 0; i < 4; ++i)
#pragma unroll
        for (int j = 0; j < 4; ++j) acc[i][j] = (f32x4){0.f, 0.f, 0.f, 0.f};

    const int rfo = ((lane & 15) * 32) + ((lane >> 4) << 3);

    for (int kt = 0; kt < K; kt += 32) {
        __syncthreads();
        gll16(Ah + ga0 + kt, &lsAh[l0]);
        gll16(Ah + ga1 + kt, &lsAh[l1]);
        gll16(Al + ga0 + kt, &lsAl[l0]);
        gll16(Al + ga1 + kt, &lsAl[l1]);
        gll16(Wh + gb0 + kt, &lsBh[l0]);
        gll16(Wh + gb1 + kt, &lsBh[l1]);
        gll16(Wl + gb0 + kt, &lsBl[l0]);
        gll16(Wl + gb1 + kt, &lsBl[l1]);
        __syncthreads();
        bf16x8 afh[4], afl[4], bfh[4], bfl[4];
#pragma unroll
        for (int i = 0; i < 4; ++i) {
            afh[i] = *(const bf16x8*)&lsAh[(wm * 64 + i * 16) * 32 + rfo];
            afl[i] = *(const bf16x8*)&lsAl[(wm * 64 + i * 16) * 32 + rfo];
        }
#pragma unroll
        for (int j = 0; j < 4; ++j) {
            bfh[j] = *(const bf16x8*)&lsBh[(wn * 64 + j * 16) * 32 + rfo];
            bfl[j] = *(const bf16x8*)&lsBl[(wn * 64 + j * 16) * 32 + rfo];
        }
#pragma unroll
        for (int i = 0; i < 4; ++i)
#pragma unroll
            for (int j = 0; j < 4; ++j) {
                acc[i][j] = __builtin_amdgcn_mfma_f32_16x16x32_bf16(afh[i], bfh[j], acc[i][j], 0, 0, 0);
                acc[i][j] = __builtin_amdgcn_mfma_f32_16x16x32_bf16(afh[i], bfl[j], acc[i][j], 0, 0, 0);
                acc[i][j] = __builtin_amdgcn_mfma_f32_16x16x32_bf16(afl[i], bfh[j], acc[i][j], 0, 0, 0);
            }
    }

    const int rbase = row0 + wm * 64 + ((lane >> 4) << 2);
    const int cbase = col0 + wn * 64 + (lane & 15);
#pragma unroll
    for (int i = 0; i < 4; ++i) {
#pragma unroll
        for (int j = 0; j < 4; ++j) {
            const int cg = cbase + j * 16;
            float bv = (SMODE == 1) ? bias[cg] : 0.f;
#pragma unroll
            for (int q = 0; q < 4; ++q) {
                const int rg = rbase + i * 16 + q;
                const size_t off = (size_t)rg * N + cg;
                float v = acc[i][j][q];
                if (SMODE == 1) {
                    float x = v + bv;
                    Cout[off] = x * sigmoid_fast(x);
                } else {
                    Cout[off] = v;
                }
            }
        }
    }
}

// ---------------------------------------------------------------------------
// plain bf16 MFMA GEMM. grid = (N/128, M/128), XCD-swizzled.
// MODE 2: +bf2f(resid)*Dv, fp32 out.  MODE 3: bf16 out, no epilogue.
// ---------------------------------------------------------------------------
template <int MODE>
__global__ __launch_bounds__(256) void mfma_gemm(
    const unsigned short* __restrict__ A, const unsigned short* __restrict__ W,
    void* __restrict__ Cout, int N,
    const unsigned short* __restrict__ resid, const float* __restrict__ Dv)
{
    constexpr int K = 768;
    __shared__ unsigned short lsA[128 * 32];
    __shared__ unsigned short lsB[128 * 32];
    const int tid  = threadIdx.x;
    const int wave = tid >> 6, lane = tid & 63;
    const int wm = wave >> 1, wn = wave & 1;
    int bx = blockIdx.x, by = blockIdx.y;
    xcd_swizzle(bx, by);
    const int row0 = by * 128, col0 = bx * 128;

    const int srow = (wave << 4) + (lane >> 2);
    const int scol = (lane & 3) << 3;
    const size_t ga0 = (size_t)(row0 + srow) * K + scol;
    const size_t ga1 = (size_t)(row0 + 64 + srow) * K + scol;
    const size_t gb0 = (size_t)(col0 + srow) * K + scol;
    const size_t gb1 = (size_t)(col0 + 64 + srow) * K + scol;
    const int l0 = srow * 32 + scol;
    const int l1 = (64 + srow) * 32 + scol;

    f32x4 acc[4][4];
#pragma unroll
    for (int i = 0; i < 4; ++i)
#pragma unroll
        for (int j = 0; j < 4; ++j) acc[i][j] = (f32x4){0.f, 0.f, 0.f, 0.f};

    const int rfo = ((lane & 15) * 32) + ((lane >> 4) << 3);

    for (int kt = 0; kt < K; kt += 32) {
        __syncthreads();
        gll16(A + ga0 + kt, &lsA[l0]);
        gll16(A + ga1 + kt, &lsA[l1]);
        gll16(W + gb0 + kt, &lsB[l0]);
        gll16(W + gb1 + kt, &lsB[l1]);
        __syncthreads();
        bf16x8 af[4], bfg[4];
#pragma unroll
        for (int i = 0; i < 4; ++i)
            af[i] = *(const bf16x8*)&lsA[(wm * 64 + i * 16) * 32 + rfo];
#pragma unroll
        for (int j = 0; j < 4; ++j)
            bfg[j] = *(const bf16x8*)&lsB[(wn * 64 + j * 16) * 32 + rfo];
#pragma unroll
        for (int i = 0; i < 4; ++i)
#pragma unroll
            for (int j = 0; j < 4; ++j)
                acc[i][j] = __builtin_amdgcn_mfma_f32_16x16x32_bf16(af[i], bfg[j], acc[i][j], 0, 0, 0);
    }

    const int rbase = row0 + wm * 64 + ((lane >> 4) << 2);
    const int cbase = col0 + wn * 64 + (lane & 15);
#pragma unroll
    for (int i = 0; i < 4; ++i) {
#pragma unroll
        for (int j = 0; j < 4; ++j) {
            const int cg = cbase + j * 16;
            const float dv = (MODE == 2) ? Dv[cg] : 0.f;
#pragma unroll
            for (int q = 0; q < 4; ++q) {
                const int rg = rbase + i * 16 + q;
                const size_t off = (size_t)rg * N + cg;
                float v = acc[i][j][q];
                if (MODE == 2) {
                    ((float*)Cout)[off] = v + bf2f(resid[off]) * dv;
                } else {
                    ((unsigned short*)Cout)[off] = f2bf(v);
                }
            }
        }
    }
}

// ---------------------------------------------------------------------------
// Causal depthwise conv (K=4) + bias + silu. fp32 in, hi/lo bf16 out.
// 4 h-channels per thread (float4 / ushort4).
// ---------------------------------------------------------------------------
__global__ __launch_bounds__(256) void conv_silu_kernel(
    const float* __restrict__ x, const float* __restrict__ w,
    const float* __restrict__ cb, unsigned short* __restrict__ yh,
    unsigned short* __restrict__ yl)
{
    int i4 = blockIdx.x * 256 + threadIdx.x;       // over MM*HH/4
    if (i4 >= MM * HH / 4) return;
    const int HQ = HH / 4;                          // 192
    int h4 = (i4 % HQ) * 4;
    int ml = i4 / HQ;
    int l  = ml % LL;
    float a0 = cb[h4], a1 = cb[h4 + 1], a2 = cb[h4 + 2], a3 = cb[h4 + 3];
#pragma unroll
    for (int j = 0; j < KK; ++j) {
        int d = (KK - 1) - j;
        if (l - d >= 0) {
            float4 xv = *(const float4*)(x + (size_t)(ml - d) * HH + h4);
            a0 = fmaf(xv.x, w[(h4 + 0) * KK + j], a0);
            a1 = fmaf(xv.y, w[(h4 + 1) * KK + j], a1);
            a2 = fmaf(xv.z, w[(h4 + 2) * KK + j], a2);
            a3 = fmaf(xv.w, w[(h4 + 3) * KK + j], a3);
        }
    }
    float y0 = a0 * sigmoid_fast(a0);
    float y1 = a1 * sigmoid_fast(a1);
    float y2 = a2 * sigmoid_fast(a2);
    float y3 = a3 * sigmoid_fast(a3);
    ushort4 vh, vl;
    split_bf(y0, vh.x, vl.x); split_bf(y1, vh.y, vl.y);
    split_bf(y2, vh.z, vl.z); split_bf(y3, vh.w, vl.w);
    *(ushort4*)(yh + (size_t)i4 * 4) = vh;
    *(ushort4*)(yl + (size_t)i4 * 4) = vl;
}

// ---------------------------------------------------------------------------
// Chunked scan with interleaved layouts:
//  heads_rt (M,768) fp32: [2p]=Rpre, [2p+1]=Thpre
//  heads_inj (M,384) bf16; bu (M,768) bf16: [2p]=Re, [2p+1]=Im
//  states (M,768) bf16 out: [2p]=xRe, [2p+1]=xIm
// ---------------------------------------------------------------------------
__global__ __launch_bounds__(256) void scan_chunk_kernel(
    const float* __restrict__ heads_rt, const unsigned short* __restrict__ heads_inj,
    const unsigned short* __restrict__ bu,
    const float* __restrict__ r_base, const float* __restrict__ th_base,
    const float* __restrict__ dt_base, const float* __restrict__ inj,
    float4* __restrict__ summA, float4* __restrict__ summB)
{
    int g = blockIdx.x * 256 + threadIdx.x;
    if (g >= NC * NCH) return;
    int t = g % NCH;
    int j = g / NCH;
    int b = t / PP, p = t - b * PP;
    const float rb = r_base[p], tb = th_base[p], il = inj[p];
    const float dt = 0.02f + 0.98f * sigmoid_fast(dt_base[p]);
    float m00 = 1.f, m01 = 0.f, m10 = 0.f, m11 = 1.f;
    float vzR = 0.f, vxR = 0.f, vzI = 0.f, vxI = 0.f;
    const int mbase = b * LL + j * CLEN;
    for (int l = 0; l < CLEN; ++l) {
        const size_t m = (size_t)(mbase + l);
        const float2 rt = *(const float2*)(heads_rt + m * 768 + 2 * p);
        const float Ip = bf2f(heads_inj[m * 384 + p]);
        const ushort2 bv = *(const ushort2*)(bu + m * 768 + 2 * p);
        const float b0 = bf2f(bv.x), b1 = bf2f(bv.y);
        float c0, c1, gdt;
        step_coef(rt.x, rt.y, Ip, rb, tb, il, dt, c0, c1, gdt);
        const float azR = gdt * b0, azI = gdt * b1;
        float nm00 = c0 * m00 - c1 * m10;
        float nm01 = c0 * m01 - c1 * m11;
        m10 = fmaf(dt, nm00, m10);
        m11 = fmaf(dt, nm01, m11);
        m00 = nm00; m01 = nm01;
        float nvzR = c0 * vzR - c1 * vxR + azR;
        vxR = fmaf(dt, nvzR, vxR); vzR = nvzR;
        float nvzI = c0 * vzI - c1 * vxI + azI;
        vxI = fmaf(dt, nvzI, vxI); vzI = nvzI;
    }
    summA[g] = make_float4(m00, m01, m10, m11);
    summB[g] = make_float4(vzR, vxR, vzI, vxI);
}

__global__ __launch_bounds__(256) void scan_mid_kernel(
    const float4* __restrict__ summA, const float4* __restrict__ summB,
    float4* __restrict__ starts)
{
    int t = blockIdx.x * 256 + threadIdx.x;
    if (t >= NCH) return;
    float zR = 0.f, xR = 0.f, zI = 0.f, xI = 0.f;
    for (int j = 0; j < NC; ++j) {
        starts[j * NCH + t] = make_float4(zR, xR, zI, xI);
        float4 Mv = summA[j * NCH + t];
        float4 Vv = summB[j * NCH + t];
        float nzR = Mv.x * zR + Mv.y * xR + Vv.x;
        float nxR = Mv.z * zR + Mv.w * xR + Vv.y;
        float nzI = Mv.x * zI + Mv.y * xI + Vv.z;
        float nxI = Mv.z * zI + Mv.w * xI + Vv.w;
        zR = nzR; xR = nxR; zI = nzI; xI = nxI;
    }
}

__global__ __launch_bounds__(256) void scan_apply_kernel(
    const float* __restrict__ heads_rt, const unsigned short* __restrict__ heads_inj,
    const unsigned short* __restrict__ bu,
    const float* __restrict__ r_base, const float* __restrict__ th_base,
    const float* __restrict__ dt_base, const float* __restrict__ inj,
    const float4* __restrict__ starts, unsigned short* __restrict__ states)
{
    int g = blockIdx.x * 256 + threadIdx.x;
    if (g >= NC * NCH) return;
    int t = g % NCH;
    int j = g / NCH;
    int b = t / PP, p = t - b * PP;
    const float rb = r_base[p], tb = th_base[p], il = inj[p];
    const float dt = 0.02f + 0.98f * sigmoid_fast(dt_base[p]);
    float4 s0 = starts[j * NCH + t];
    float zR = s0.x, xR = s0.y, zI = s0.z, xI = s0.w;
    const int mbase = b * LL + j * CLEN;
    for (int l = 0; l < CLEN; ++l) {
        const size_t m = (size_t)(mbase + l);
        const float2 rt = *(const float2*)(heads_rt + m * 768 + 2 * p);
        const float Ip = bf2f(heads_inj[m * 384 + p]);
        const ushort2 bv = *(const ushort2*)(bu + m * 768 + 2 * p);
        const float b0 = bf2f(bv.x), b1 = bf2f(bv.y);
        float c0, c1, gdt;
        step_coef(rt.x, rt.y, Ip, rb, tb, il, dt, c0, c1, gdt);
        zR = c0 * zR - c1 * xR + gdt * b0;
        xR = fmaf(dt, zR, xR);
        zI = c0 * zI - c1 * xI + gdt * b1;
        xI = fmaf(dt, zI, xI);
        ushort2 sv;
        sv.x = f2bf(xR);
        sv.y = f2bf(xI);
        *(ushort2*)(states + m * 768 + 2 * p) = sv;
    }
}

// ---------------------------------------------------------------------------
extern "C" void kernel_launch(void* const* d_in, const int* in_sizes, int n_in,
                              void* d_out, int out_size, void* d_ws, size_t ws_size,
                              hipStream_t stream)
{
    const float* inputs  = (const float*)d_in[0];
    const float* Wl      = (const float*)d_in[1];
    const float* bl      = (const float*)d_in[2];
    const float* conv_w  = (const float*)d_in[3];
    const float* conv_b  = (const float*)d_in[4];
    const float* Wr      = (const float*)d_in[5];
    const float* Wth     = (const float*)d_in[6];
    const float* Winj    = (const float*)d_in[7];
    const float* r_base  = (const float*)d_in[8];
    const float* th_base = (const float*)d_in[9];
    const float* dt_base = (const float*)d_in[10];
    const float* inj_l   = (const float*)d_in[11];
    const float* Bp      = (const float*)d_in[12];
    const float* Cp      = (const float*)d_in[13];
    const float* Dv      = (const float*)d_in[14];
    float* out = (float*)d_out;

    // ---- workspace layout (lifetime-aliased) ----
    const size_t NB = 768 * 768, NI = 384 * 768, NMH = (size_t)MM * 768;
    unsigned short* wlh    = (unsigned short*)d_ws;
    unsigned short* wll    = wlh + NB;
    unsigned short* wrth_h = wll + NB;
    unsigned short* wrth_l = wrth_h + NB;
    unsigned short* winj   = wrth_l + NB;
    unsigned short* wb     = winj + NI;
    unsigned short* wc     = wb + NB;
    unsigned short* inh    = wc + NB;            // MM*768 bf16, live t3..t9
    unsigned short* inl    = inh + NMH;          // live t3 only -> states later
    unsigned short* f2h    = inl + NMH;          // conv out hi, live t4..t5
    unsigned short* f2l    = f2h + NMH;          // conv out lo
    unsigned short* hinj   = f2l + NMH;          // heads_inj bf16 MM*384
    float* f1       = (float*)(hinj + (size_t)MM * 384);   // enc out fp32 (96MB)
    float* heads_rt = f1;                        // overlays f1 (dead after conv)
    float4* summA = (float4*)(f1 + NMH);
    float4* summB = summA + (size_t)NC * NCH;
    float4* starts= summB + (size_t)NC * NCH;
    unsigned short* bu = (unsigned short*)d_out; // bf16 MM*768, dead after scan
    unsigned short* states = inl;                // overlays dead inl

    // t1. repack weights ; t2. split-convert inputs
    {
        int total = (int)(4 * NB + NI);
        repack_kernel<<<(total + 255) / 256, 256, 0, stream>>>(
            Wl, Wr, Wth, Winj, Bp, Cp, wlh, wll, wrth_h, wrth_l, winj, wb, wc);
        int n4 = (int)(NMH / 4);
        split_convert_kernel<<<(n4 + 255) / 256, 256, 0, stream>>>(inputs, inh, inl, n4);
    }
    // t3. encoder (split): f1 = silu(inputs @ Wl^T + bl)  [fp32]
    mfma_gemm_split<1><<<dim3(6, MM / 128), 256, 0, stream>>>(
        inh, inl, wlh, wll, f1, 768, bl);
    // t4. conv + silu: f1 -> f2 hi/lo
    conv_silu_kernel<<<(MM * HH / 4 + 255) / 256, 256, 0, stream>>>(f1, conv_w, conv_b, f2h, f2l);
    // t5a. R/Th heads (split, interleaved rows): heads_rt [fp32, overlays f1]
    mfma_gemm_split<0><<<dim3(6, MM / 128), 256, 0, stream>>>(
        f2h, f2l, wrth_h, wrth_l, heads_rt, 768, nullptr);
    // t5b. Inj head (plain): hinj = f2h @ Winj^T  [bf16]
    mfma_gemm<3><<<dim3(3, MM / 128), 256, 0, stream>>>(
        f2h, winj, (void*)hinj, 384, nullptr, nullptr);
    // t6. input projection (plain, interleaved rows): bu [bf16, in d_out]
    mfma_gemm<3><<<dim3(6, MM / 128), 256, 0, stream>>>(
        inh, wb, (void*)bu, 768, nullptr, nullptr);
    // t7. chunked scan
    scan_chunk_kernel<<<(NC * NCH) / 256, 256, 0, stream>>>(
        heads_rt, hinj, bu, r_base, th_base, dt_base, inj_l, summA, summB);
    scan_mid_kernel<<<(NCH + 255) / 256, 256, 0, stream>>>(summA, summB, starts);
    scan_apply_kernel<<<(NC * NCH) / 256, 256, 0, stream>>>(
        heads_rt, hinj, bu, r_base, th_base, dt_base, inj_l, starts, states);
    // t9. output projection + residual (resid read as bf16 inh)
    mfma_gemm<2><<<dim3(6, MM / 128), 256, 0, stream>>>(
        states, wc, (void*)out, 768, inh, Dv);
}

// Round 10
// 641.117 us; speedup vs baseline: 1.3611x; 1.2057x over previous
//
#include <hip/hip_runtime.h>
#include <math.h>

#define PP 384
#define HH 768
#define KK 4
#define BB 16
#define LL 2048
#define MM (BB*LL)   // 32768
#define NCH (BB*PP)  // 6144
#define NC 32
#define CLEN (LL/NC) // 64
#define CRUN 32      // conv rolling-window run length

typedef __attribute__((ext_vector_type(8))) short bf16x8;
typedef __attribute__((ext_vector_type(4))) float f32x4;

__device__ __forceinline__ float sigmoid_fast(float x) { return 1.0f / (1.0f + __expf(-x)); }

__device__ __forceinline__ float bf2f(unsigned short h) {
    return __uint_as_float(((unsigned int)h) << 16);
}
__device__ __forceinline__ unsigned short f2bf(float x) {
    unsigned int u = __float_as_uint(x);
    u += 0x7fff + ((u >> 16) & 1);          // round-to-nearest-even
    return (unsigned short)(u >> 16);
}
// split x into hi (bf16) and lo (bf16 of residual): x ≈ hi + lo, err ~2^-17
__device__ __forceinline__ void split_bf(float x, unsigned short& hi, unsigned short& lo) {
    hi = f2bf(x);
    lo = f2bf(x - bf2f(hi));
}

__device__ __forceinline__ void gll16(const void* g, void* l) {
    __builtin_amdgcn_global_load_lds(
        (const __attribute__((address_space(1))) void*)g,
        (__attribute__((address_space(3))) void*)l, 16, 0, 0);
}

// Bijective XCD-aware block swizzle (m204): each XCD owns consecutive work
// units -> A row-panels fetched once chip-wide, W resident in per-XCD L2.
__device__ __forceinline__ void xcd_swizzle(int& bx, int& by) {
    const int gx = (int)gridDim.x;
    const int nwg = gx * (int)gridDim.y;
    const int orig = by * gx + bx;
    const int q = nwg >> 3, r = nwg & 7;
    const int xcd = orig & 7, off = orig >> 3;
    const int swz = (xcd < r ? xcd * (q + 1) : r * (q + 1) + (xcd - r) * q) + off;
    bx = swz % gx;
    by = swz / gx;
}

// Per-step scalar coefficients (state-independent), fast-math, used
// identically in compose and apply phases.
__device__ __forceinline__ void step_coef(float Rp, float Tp, float Ip,
    float rb, float tb, float il, float dt,
    float& c0, float& c1, float& gdt)
{
    const float PIf = 3.14159265358979323846f;
    float r  = sigmoid_fast(rb + Rp);
    float t  = tb + Tp;
    float e2 = __expf(2.0f * fabsf(t));
    float th = PIf * copysignf(1.0f - 2.0f / (e2 + 1.0f), t);
    float ct = __cosf(th);
    float r2 = fmaxf(r * r, 1e-8f);
    float Ac = (r2 - 2.0f * r * ct + 1.0f) / (dt * dt * r2);
    float Gc = (1.0f - r2) / (dt * r2);
    float S  = 1.0f / (1.0f + dt * Gc);
    float gate = sigmoid_fast(il + Ip);
    c0 = S;
    c1 = S * (dt * Ac);
    gdt = S * dt * gate;
}

// ---------------------------------------------------------------------------
// Weight repack (interleaved layouts for scan-friendly reads):
//  wlh/wll (768x768)       = Wl split hi/lo
//  wrth h/l (768x768)      : row 2p=Wr[p], row 2p+1=Wth[p]  (split hi/lo)
//  winj (384x768) bf16     = Winj
//  wb (768x768) bf16       : row 2p=BRe[p], row 2p+1=BIm[p]
//  wc (768x768) bf16       : wc[i] = (i&1) ? -CIm : CRe  (natural Cp order)
// ---------------------------------------------------------------------------
__global__ __launch_bounds__(256) void repack_kernel(
    const float* __restrict__ Wl, const float* __restrict__ Wr,
    const float* __restrict__ Wth, const float* __restrict__ Winj,
    const float* __restrict__ Bp, const float* __restrict__ Cp,
    unsigned short* __restrict__ wlh, unsigned short* __restrict__ wll,
    unsigned short* __restrict__ wrth_h, unsigned short* __restrict__ wrth_l,
    unsigned short* __restrict__ winj,
    unsigned short* __restrict__ wb, unsigned short* __restrict__ wc)
{
    int i = blockIdx.x * 256 + threadIdx.x;
    const int NB = 768 * 768, NI = 384 * 768;
    if (i < NB) { split_bf(Wl[i], wlh[i], wll[i]); return; }
    i -= NB;
    if (i < NB) {    // interleaved [Wr;Wth]
        int n = i / 768, k = i - n * 768;
        int p = n >> 1;
        float v = (n & 1) ? Wth[p * 768 + k] : Wr[p * 768 + k];
        split_bf(v, wrth_h[i], wrth_l[i]);
        return;
    }
    i -= NB;
    if (i < NI) { winj[i] = f2bf(Winj[i]); return; }
    i -= NI;
    if (i < NB) {    // interleaved [BRe;BIm]
        int n = i / 768, k = i - n * 768;
        wb[i] = f2bf(Bp[(size_t)(n >> 1) * 1536 + k * 2 + (n & 1)]);
        return;
    }
    i -= NB;
    if (i < NB) {    // col-interleaved [CRe|-CIm] == sign-flipped natural Cp
        wc[i] = f2bf((i & 1) ? -Cp[i] : Cp[i]);
    }
}

// inputs -> hi/lo split buffers
__global__ __launch_bounds__(256) void split_convert_kernel(
    const float* __restrict__ in, unsigned short* __restrict__ outh,
    unsigned short* __restrict__ outl, int n4)
{
    int i = blockIdx.x * 256 + threadIdx.x;
    if (i >= n4) return;
    float4 a = ((const float4*)in)[i];
    ushort4 h, l;
    split_bf(a.x, h.x, l.x); split_bf(a.y, h.y, l.y);
    split_bf(a.z, h.z, l.z); split_bf(a.w, h.w, l.w);
    ((ushort4*)outh)[i] = h;
    ((ushort4*)outl)[i] = l;
}

// ---------------------------------------------------------------------------
// SPLIT-PRECISION bf16 MFMA GEMM: C = (Ah+Al) @ (Wh+Wl)^T  (3 MFMAs/k-step)
// grid = (N/128, M/128), XCD-swizzled.
// SMODE 0: fp32 out. SMODE 1: +bias, silu, fp32 out.
// ---------------------------------------------------------------------------
template <int SMODE>
__global__ __launch_bounds__(256) void mfma_gemm_split(
    const unsigned short* __restrict__ Ah, const unsigned short* __restrict__ Al,
    const unsigned short* __restrict__ Wh, const unsigned short* __restrict__ Wl,
    float* __restrict__ Cout, int N, const float* __restrict__ bias)
{
    constexpr int K = 768;
    __shared__ unsigned short lsAh[128 * 32];
    __shared__ unsigned short lsAl[128 * 32];
    __shared__ unsigned short lsBh[128 * 32];
    __shared__ unsigned short lsBl[128 * 32];
    const int tid  = threadIdx.x;
    const int wave = tid >> 6, lane = tid & 63;
    const int wm = wave >> 1, wn = wave & 1;
    int bx = blockIdx.x, by = blockIdx.y;
    xcd_swizzle(bx, by);
    const int row0 = by * 128, col0 = bx * 128;

    const int srow = (wave << 4) + (lane >> 2);    // 0..63
    const int scol = (lane & 3) << 3;              // 0,8,16,24
    const size_t ga0 = (size_t)(row0 + srow) * K + scol;
    const size_t ga1 = (size_t)(row0 + 64 + srow) * K + scol;
    const size_t gb0 = (size_t)(col0 + srow) * K + scol;
    const size_t gb1 = (size_t)(col0 + 64 + srow) * K + scol;
    const int l0 = srow * 32 + scol;
    const int l1 = (64 + srow) * 32 + scol;

    f32x4 acc[4][4];
#pragma unroll
    for (int i = 0; i < 4; ++i)
#pragma unroll
        for (int j = 0; j < 4; ++j) acc[i][j] = (f32x4){0.f, 0.f, 0.f, 0.f};

    const int rfo = ((lane & 15) * 32) + ((lane >> 4) << 3);

    for (int kt = 0; kt < K; kt += 32) {
        __syncthreads();
        gll16(Ah + ga0 + kt, &lsAh[l0]);
        gll16(Ah + ga1 + kt, &lsAh[l1]);
        gll16(Al + ga0 + kt, &lsAl[l0]);
        gll16(Al + ga1 + kt, &lsAl[l1]);
        gll16(Wh + gb0 + kt, &lsBh[l0]);
        gll16(Wh + gb1 + kt, &lsBh[l1]);
        gll16(Wl + gb0 + kt, &lsBl[l0]);
        gll16(Wl + gb1 + kt, &lsBl[l1]);
        __syncthreads();
        bf16x8 afh[4], afl[4], bfh[4], bfl[4];
#pragma unroll
        for (int i = 0; i < 4; ++i) {
            afh[i] = *(const bf16x8*)&lsAh[(wm * 64 + i * 16) * 32 + rfo];
            afl[i] = *(const bf16x8*)&lsAl[(wm * 64 + i * 16) * 32 + rfo];
        }
#pragma unroll
        for (int j = 0; j < 4; ++j) {
            bfh[j] = *(const bf16x8*)&lsBh[(wn * 64 + j * 16) * 32 + rfo];
            bfl[j] = *(const bf16x8*)&lsBl[(wn * 64 + j * 16) * 32 + rfo];
        }
#pragma unroll
        for (int i = 0; i < 4; ++i)
#pragma unroll
            for (int j = 0; j < 4; ++j) {
                acc[i][j] = __builtin_amdgcn_mfma_f32_16x16x32_bf16(afh[i], bfh[j], acc[i][j], 0, 0, 0);
                acc[i][j] = __builtin_amdgcn_mfma_f32_16x16x32_bf16(afh[i], bfl[j], acc[i][j], 0, 0, 0);
                acc[i][j] = __builtin_amdgcn_mfma_f32_16x16x32_bf16(afl[i], bfh[j], acc[i][j], 0, 0, 0);
            }
    }

    const int rbase = row0 + wm * 64 + ((lane >> 4) << 2);
    const int cbase = col0 + wn * 64 + (lane & 15);
#pragma unroll
    for (int i = 0; i < 4; ++i) {
#pragma unroll
        for (int j = 0; j < 4; ++j) {
            const int cg = cbase + j * 16;
            float bv = (SMODE == 1) ? bias[cg] : 0.f;
#pragma unroll
            for (int q = 0; q < 4; ++q) {
                const int rg = rbase + i * 16 + q;
                const size_t off = (size_t)rg * N + cg;
                float v = acc[i][j][q];
                if (SMODE == 1) {
                    float x = v + bv;
                    Cout[off] = x * sigmoid_fast(x);
                } else {
                    Cout[off] = v;
                }
            }
        }
    }
}

// ---------------------------------------------------------------------------
// plain bf16 MFMA GEMM. grid = (N/128, M/128), XCD-swizzled.
// MODE 2: +bf2f(resid)*Dv, fp32 out.  MODE 3: bf16 out, no epilogue.
// ---------------------------------------------------------------------------
template <int MODE>
__global__ __launch_bounds__(256) void mfma_gemm(
    const unsigned short* __restrict__ A, const unsigned short* __restrict__ W,
    void* __restrict__ Cout, int N,
    const unsigned short* __restrict__ resid, const float* __restrict__ Dv)
{
    constexpr int K = 768;
    __shared__ unsigned short lsA[128 * 32];
    __shared__ unsigned short lsB[128 * 32];
    const int tid  = threadIdx.x;
    const int wave = tid >> 6, lane = tid & 63;
    const int wm = wave >> 1, wn = wave & 1;
    int bx = blockIdx.x, by = blockIdx.y;
    xcd_swizzle(bx, by);
    const int row0 = by * 128, col0 = bx * 128;

    const int srow = (wave << 4) + (lane >> 2);
    const int scol = (lane & 3) << 3;
    const size_t ga0 = (size_t)(row0 + srow) * K + scol;
    const size_t ga1 = (size_t)(row0 + 64 + srow) * K + scol;
    const size_t gb0 = (size_t)(col0 + srow) * K + scol;
    const size_t gb1 = (size_t)(col0 + 64 + srow) * K + scol;
    const int l0 = srow * 32 + scol;
    const int l1 = (64 + srow) * 32 + scol;

    f32x4 acc[4][4];
#pragma unroll
    for (int i = 0; i < 4; ++i)
#pragma unroll
        for (int j = 0; j < 4; ++j) acc[i][j] = (f32x4){0.f, 0.f, 0.f, 0.f};

    const int rfo = ((lane & 15) * 32) + ((lane >> 4) << 3);

    for (int kt = 0; kt < K; kt += 32) {
        __syncthreads();
        gll16(A + ga0 + kt, &lsA[l0]);
        gll16(A + ga1 + kt, &lsA[l1]);
        gll16(W + gb0 + kt, &lsB[l0]);
        gll16(W + gb1 + kt, &lsB[l1]);
        __syncthreads();
        bf16x8 af[4], bfg[4];
#pragma unroll
        for (int i = 0; i < 4; ++i)
            af[i] = *(const bf16x8*)&lsA[(wm * 64 + i * 16) * 32 + rfo];
#pragma unroll
        for (int j = 0; j < 4; ++j)
            bfg[j] = *(const bf16x8*)&lsB[(wn * 64 + j * 16) * 32 + rfo];
#pragma unroll
        for (int i = 0; i < 4; ++i)
#pragma unroll
            for (int j = 0; j < 4; ++j)
                acc[i][j] = __builtin_amdgcn_mfma_f32_16x16x32_bf16(af[i], bfg[j], acc[i][j], 0, 0, 0);
    }

    const int rbase = row0 + wm * 64 + ((lane >> 4) << 2);
    const int cbase = col0 + wn * 64 + (lane & 15);
#pragma unroll
    for (int i = 0; i < 4; ++i) {
#pragma unroll
        for (int j = 0; j < 4; ++j) {
            const int cg = cbase + j * 16;
            const float dv = (MODE == 2) ? Dv[cg] : 0.f;
#pragma unroll
            for (int q = 0; q < 4; ++q) {
                const int rg = rbase + i * 16 + q;
                const size_t off = (size_t)rg * N + cg;
                float v = acc[i][j][q];
                if (MODE == 2) {
                    ((float*)Cout)[off] = v + bf2f(resid[off]) * dv;
                } else {
                    ((unsigned short*)Cout)[off] = f2bf(v);
                }
            }
        }
    }
}

// ---------------------------------------------------------------------------
// Causal depthwise conv (K=4) + bias + silu, ROLLING WINDOW.
// Each thread: one channel h, CRUN consecutive l. Each f1 element read once.
// Wave = 64 consecutive h (coalesced). Zero-primed window at l==0 is
// bit-identical to the reference's skipped taps (adds w*0 in same fmaf order).
// ---------------------------------------------------------------------------
__global__ __launch_bounds__(256) void conv_silu_kernel(
    const float* __restrict__ x, const float* __restrict__ w,
    const float* __restrict__ cb, unsigned short* __restrict__ yh,
    unsigned short* __restrict__ yl)
{
    const int NRUN = MM / CRUN;                 // 1024
    int tid = blockIdx.x * 256 + threadIdx.x;   // over HH * NRUN
    if (tid >= HH * NRUN) return;
    const int h   = tid % HH;
    const int run = tid / HH;
    const int ml0 = run * CRUN;                 // global row start
    const int l0  = ml0 % LL;                   // within-sequence start
    const float w0 = w[h * KK + 0], w1 = w[h * KK + 1];
    const float w2 = w[h * KK + 2], w3 = w[h * KK + 3];
    const float bias = cb[h];
    float x0, x1, x2;                           // window: x[l-3], x[l-2], x[l-1]
    if (l0 == 0) {
        x0 = 0.f; x1 = 0.f; x2 = 0.f;
    } else {
        x0 = x[(size_t)(ml0 - 3) * HH + h];
        x1 = x[(size_t)(ml0 - 2) * HH + h];
        x2 = x[(size_t)(ml0 - 1) * HH + h];
    }
    for (int i = 0; i < CRUN; ++i) {
        const size_t m = (size_t)(ml0 + i);
        const float x3 = x[m * HH + h];
        float acc = bias;
        acc = fmaf(x0, w0, acc);
        acc = fmaf(x1, w1, acc);
        acc = fmaf(x2, w2, acc);
        acc = fmaf(x3, w3, acc);
        const float y = acc * sigmoid_fast(acc);
        unsigned short hi, lo;
        split_bf(y, hi, lo);
        yh[m * HH + h] = hi;
        yl[m * HH + h] = lo;
        x0 = x1; x1 = x2; x2 = x3;
    }
}

// ---------------------------------------------------------------------------
// Chunked scan with interleaved layouts:
//  heads_rt (M,768) fp32: [2p]=Rpre, [2p+1]=Thpre
//  heads_inj (M,384) bf16; bu (M,768) bf16: [2p]=Re, [2p+1]=Im
//  states (M,768) bf16 out: [2p]=xRe, [2p+1]=xIm
// ---------------------------------------------------------------------------
__global__ __launch_bounds__(256) void scan_chunk_kernel(
    const float* __restrict__ heads_rt, const unsigned short* __restrict__ heads_inj,
    const unsigned short* __restrict__ bu,
    const float* __restrict__ r_base, const float* __restrict__ th_base,
    const float* __restrict__ dt_base, const float* __restrict__ inj,
    float4* __restrict__ summA, float4* __restrict__ summB)
{
    int g = blockIdx.x * 256 + threadIdx.x;
    if (g >= NC * NCH) return;
    int t = g % NCH;
    int j = g / NCH;
    int b = t / PP, p = t - b * PP;
    const float rb = r_base[p], tb = th_base[p], il = inj[p];
    const float dt = 0.02f + 0.98f * sigmoid_fast(dt_base[p]);
    float m00 = 1.f, m01 = 0.f, m10 = 0.f, m11 = 1.f;
    float vzR = 0.f, vxR = 0.f, vzI = 0.f, vxI = 0.f;
    const int mbase = b * LL + j * CLEN;
    for (int l = 0; l < CLEN; ++l) {
        const size_t m = (size_t)(mbase + l);
        const float2 rt = *(const float2*)(heads_rt + m * 768 + 2 * p);
        const float Ip = bf2f(heads_inj[m * 384 + p]);
        const ushort2 bv = *(const ushort2*)(bu + m * 768 + 2 * p);
        const float b0 = bf2f(bv.x), b1 = bf2f(bv.y);
        float c0, c1, gdt;
        step_coef(rt.x, rt.y, Ip, rb, tb, il, dt, c0, c1, gdt);
        const float azR = gdt * b0, azI = gdt * b1;
        float nm00 = c0 * m00 - c1 * m10;
        float nm01 = c0 * m01 - c1 * m11;
        m10 = fmaf(dt, nm00, m10);
        m11 = fmaf(dt, nm01, m11);
        m00 = nm00; m01 = nm01;
        float nvzR = c0 * vzR - c1 * vxR + azR;
        vxR = fmaf(dt, nvzR, vxR); vzR = nvzR;
        float nvzI = c0 * vzI - c1 * vxI + azI;
        vxI = fmaf(dt, nvzI, vxI); vzI = nvzI;
    }
    summA[g] = make_float4(m00, m01, m10, m11);
    summB[g] = make_float4(vzR, vxR, vzI, vxI);
}

__global__ __launch_bounds__(256) void scan_mid_kernel(
    const float4* __restrict__ summA, const float4* __restrict__ summB,
    float4* __restrict__ starts)
{
    int t = blockIdx.x * 256 + threadIdx.x;
    if (t >= NCH) return;
    float zR = 0.f, xR = 0.f, zI = 0.f, xI = 0.f;
    for (int j = 0; j < NC; ++j) {
        starts[j * NCH + t] = make_float4(zR, xR, zI, xI);
        float4 Mv = summA[j * NCH + t];
        float4 Vv = summB[j * NCH + t];
        float nzR = Mv.x * zR + Mv.y * xR + Vv.x;
        float nxR = Mv.z * zR + Mv.w * xR + Vv.y;
        float nzI = Mv.x * zI + Mv.y * xI + Vv.z;
        float nxI = Mv.z * zI + Mv.w * xI + Vv.w;
        zR = nzR; xR = nxR; zI = nzI; xI = nxI;
    }
}

__global__ __launch_bounds__(256) void scan_apply_kernel(
    const float* __restrict__ heads_rt, const unsigned short* __restrict__ heads_inj,
    const unsigned short* __restrict__ bu,
    const float* __restrict__ r_base, const float* __restrict__ th_base,
    const float* __restrict__ dt_base, const float* __restrict__ inj,
    const float4* __restrict__ starts, unsigned short* __restrict__ states)
{
    int g = blockIdx.x * 256 + threadIdx.x;
    if (g >= NC * NCH) return;
    int t = g % NCH;
    int j = g / NCH;
    int b = t / PP, p = t - b * PP;
    const float rb = r_base[p], tb = th_base[p], il = inj[p];
    const float dt = 0.02f + 0.98f * sigmoid_fast(dt_base[p]);
    float4 s0 = starts[j * NCH + t];
    float zR = s0.x, xR = s0.y, zI = s0.z, xI = s0.w;
    const int mbase = b * LL + j * CLEN;
    for (int l = 0; l < CLEN; ++l) {
        const size_t m = (size_t)(mbase + l);
        const float2 rt = *(const float2*)(heads_rt + m * 768 + 2 * p);
        const float Ip = bf2f(heads_inj[m * 384 + p]);
        const ushort2 bv = *(const ushort2*)(bu + m * 768 + 2 * p);
        const float b0 = bf2f(bv.x), b1 = bf2f(bv.y);
        float c0, c1, gdt;
        step_coef(rt.x, rt.y, Ip, rb, tb, il, dt, c0, c1, gdt);
        zR = c0 * zR - c1 * xR + gdt * b0;
        xR = fmaf(dt, zR, xR);
        zI = c0 * zI - c1 * xI + gdt * b1;
        xI = fmaf(dt, zI, xI);
        ushort2 sv;
        sv.x = f2bf(xR);
        sv.y = f2bf(xI);
        *(ushort2*)(states + m * 768 + 2 * p) = sv;
    }
}

// ---------------------------------------------------------------------------
extern "C" void kernel_launch(void* const* d_in, const int* in_sizes, int n_in,
                              void* d_out, int out_size, void* d_ws, size_t ws_size,
                              hipStream_t stream)
{
    const float* inputs  = (const float*)d_in[0];
    const float* Wl      = (const float*)d_in[1];
    const float* bl      = (const float*)d_in[2];
    const float* conv_w  = (const float*)d_in[3];
    const float* conv_b  = (const float*)d_in[4];
    const float* Wr      = (const float*)d_in[5];
    const float* Wth     = (const float*)d_in[6];
    const float* Winj    = (const float*)d_in[7];
    const float* r_base  = (const float*)d_in[8];
    const float* th_base = (const float*)d_in[9];
    const float* dt_base = (const float*)d_in[10];
    const float* inj_l   = (const float*)d_in[11];
    const float* Bp      = (const float*)d_in[12];
    const float* Cp      = (const float*)d_in[13];
    const float* Dv      = (const float*)d_in[14];
    float* out = (float*)d_out;

    // ---- workspace layout (lifetime-aliased) ----
    const size_t NB = 768 * 768, NI = 384 * 768, NMH = (size_t)MM * 768;
    unsigned short* wlh    = (unsigned short*)d_ws;
    unsigned short* wll    = wlh + NB;
    unsigned short* wrth_h = wll + NB;
    unsigned short* wrth_l = wrth_h + NB;
    unsigned short* winj   = wrth_l + NB;
    unsigned short* wb     = winj + NI;
    unsigned short* wc     = wb + NB;
    unsigned short* inh    = wc + NB;            // MM*768 bf16, live t3..t9
    unsigned short* inl    = inh + NMH;          // live t3 only -> states later
    unsigned short* f2h    = inl + NMH;          // conv out hi, live t4..t5
    unsigned short* f2l    = f2h + NMH;          // conv out lo
    unsigned short* hinj   = f2l + NMH;          // heads_inj bf16 MM*384
    float* f1       = (float*)(hinj + (size_t)MM * 384);   // enc out fp32 (96MB)
    float* heads_rt = f1;                        // overlays f1 (dead after conv)
    float4* summA = (float4*)(f1 + NMH);
    float4* summB = summA + (size_t)NC * NCH;
    float4* starts= summB + (size_t)NC * NCH;
    unsigned short* bu = (unsigned short*)d_out; // bf16 MM*768, dead after scan
    unsigned short* states = inl;                // overlays dead inl

    // t1. repack weights ; t2. split-convert inputs
    {
        int total = (int)(4 * NB + NI);
        repack_kernel<<<(total + 255) / 256, 256, 0, stream>>>(
            Wl, Wr, Wth, Winj, Bp, Cp, wlh, wll, wrth_h, wrth_l, winj, wb, wc);
        int n4 = (int)(NMH / 4);
        split_convert_kernel<<<(n4 + 255) / 256, 256, 0, stream>>>(inputs, inh, inl, n4);
    }
    // t3. encoder (split): f1 = silu(inputs @ Wl^T + bl)  [fp32]
    mfma_gemm_split<1><<<dim3(6, MM / 128), 256, 0, stream>>>(
        inh, inl, wlh, wll, f1, 768, bl);
    // t4. conv + silu (rolling window): f1 -> f2 hi/lo
    {
        int nthr = HH * (MM / CRUN);
        conv_silu_kernel<<<(nthr + 255) / 256, 256, 0, stream>>>(f1, conv_w, conv_b, f2h, f2l);
    }
    // t5a. R/Th heads (split, interleaved rows): heads_rt [fp32, overlays f1]
    mfma_gemm_split<0><<<dim3(6, MM / 128), 256, 0, stream>>>(
        f2h, f2l, wrth_h, wrth_l, heads_rt, 768, nullptr);
    // t5b. Inj head (plain): hinj = f2h @ Winj^T  [bf16]
    mfma_gemm<3><<<dim3(3, MM / 128), 256, 0, stream>>>(
        f2h, winj, (void*)hinj, 384, nullptr, nullptr);
    // t6. input projection (plain, interleaved rows): bu [bf16, in d_out]
    mfma_gemm<3><<<dim3(6, MM / 128), 256, 0, stream>>>(
        inh, wb, (void*)bu, 768, nullptr, nullptr);
    // t7. chunked scan
    scan_chunk_kernel<<<(NC * NCH) / 256, 256, 0, stream>>>(
        heads_rt, hinj, bu, r_base, th_base, dt_base, inj_l, summA, summB);
    scan_mid_kernel<<<(NCH + 255) / 256, 256, 0, stream>>>(summA, summB, starts);
    scan_apply_kernel<<<(NC * NCH) / 256, 256, 0, stream>>>(
        heads_rt, hinj, bu, r_base, th_base, dt_base, inj_l, starts, states);
    // t9. output projection + residual (resid read as bf16 inh)
    mfma_gemm<2><<<dim3(6, MM / 128), 256, 0, stream>>>(
        states, wc, (void*)out, 768, inh, Dv);
}

// Round 11
// 614.671 us; speedup vs baseline: 1.4197x; 1.0430x over previous
//
#include <hip/hip_runtime.h>
#include <math.h>

#define PP 384
#define HH 768
#define KK 4
#define BB 16
#define LL 2048
#define MM (BB*LL)   // 32768
#define NCH (BB*PP)  // 6144
#define NC 64
#define CLEN (LL/NC) // 32
#define CRUN 32      // conv rolling-window run length

typedef __attribute__((ext_vector_type(8))) short bf16x8;
typedef __attribute__((ext_vector_type(4))) float f32x4;

__device__ __forceinline__ float sigmoid_fast(float x) { return 1.0f / (1.0f + __expf(-x)); }

__device__ __forceinline__ float bf2f(unsigned short h) {
    return __uint_as_float(((unsigned int)h) << 16);
}
__device__ __forceinline__ unsigned short f2bf(float x) {
    unsigned int u = __float_as_uint(x);
    u += 0x7fff + ((u >> 16) & 1);          // round-to-nearest-even
    return (unsigned short)(u >> 16);
}
// split x into hi (bf16) and lo (bf16 of residual): x ≈ hi + lo, err ~2^-17
__device__ __forceinline__ void split_bf(float x, unsigned short& hi, unsigned short& lo) {
    hi = f2bf(x);
    lo = f2bf(x - bf2f(hi));
}

__device__ __forceinline__ void gll16(const void* g, void* l) {
    __builtin_amdgcn_global_load_lds(
        (const __attribute__((address_space(1))) void*)g,
        (__attribute__((address_space(3))) void*)l, 16, 0, 0);
}

// Bijective XCD-aware block swizzle (m204): each XCD owns consecutive work
// units -> A row-panels fetched once chip-wide, W resident in per-XCD L2.
__device__ __forceinline__ void xcd_swizzle(int& bx, int& by) {
    const int gx = (int)gridDim.x;
    const int nwg = gx * (int)gridDim.y;
    const int orig = by * gx + bx;
    const int q = nwg >> 3, r = nwg & 7;
    const int xcd = orig & 7, off = orig >> 3;
    const int swz = (xcd < r ? xcd * (q + 1) : r * (q + 1) + (xcd - r) * q) + off;
    bx = swz % gx;
    by = swz / gx;
}

// Per-step scalar coefficients (state-independent), fast-math, used
// identically wherever evaluated.
__device__ __forceinline__ void step_coef(float Rp, float Tp, float Ip,
    float rb, float tb, float il, float dt,
    float& c0, float& c1, float& gdt)
{
    const float PIf = 3.14159265358979323846f;
    float r  = sigmoid_fast(rb + Rp);
    float t  = tb + Tp;
    float e2 = __expf(2.0f * fabsf(t));
    float th = PIf * copysignf(1.0f - 2.0f / (e2 + 1.0f), t);
    float ct = __cosf(th);
    float r2 = fmaxf(r * r, 1e-8f);
    float Ac = (r2 - 2.0f * r * ct + 1.0f) / (dt * dt * r2);
    float Gc = (1.0f - r2) / (dt * r2);
    float S  = 1.0f / (1.0f + dt * Gc);
    float gate = sigmoid_fast(il + Ip);
    c0 = S;
    c1 = S * (dt * Ac);
    gdt = S * dt * gate;
}

// ---------------------------------------------------------------------------
// Weight repack (interleaved layouts for scan-friendly reads):
//  wlh/wll (768x768)       = Wl split hi/lo
//  wrth h/l (768x768)      : row 2p=Wr[p], row 2p+1=Wth[p]  (split hi/lo)
//  winj (384x768) bf16     = Winj
//  wb (768x768) bf16       : row 2p=BRe[p], row 2p+1=BIm[p]
//  wc (768x768) bf16       : wc[i] = (i&1) ? -CIm : CRe  (natural Cp order)
// ---------------------------------------------------------------------------
__global__ __launch_bounds__(256) void repack_kernel(
    const float* __restrict__ Wl, const float* __restrict__ Wr,
    const float* __restrict__ Wth, const float* __restrict__ Winj,
    const float* __restrict__ Bp, const float* __restrict__ Cp,
    unsigned short* __restrict__ wlh, unsigned short* __restrict__ wll,
    unsigned short* __restrict__ wrth_h, unsigned short* __restrict__ wrth_l,
    unsigned short* __restrict__ winj,
    unsigned short* __restrict__ wb, unsigned short* __restrict__ wc)
{
    int i = blockIdx.x * 256 + threadIdx.x;
    const int NB = 768 * 768, NI = 384 * 768;
    if (i < NB) { split_bf(Wl[i], wlh[i], wll[i]); return; }
    i -= NB;
    if (i < NB) {    // interleaved [Wr;Wth]
        int n = i / 768, k = i - n * 768;
        int p = n >> 1;
        float v = (n & 1) ? Wth[p * 768 + k] : Wr[p * 768 + k];
        split_bf(v, wrth_h[i], wrth_l[i]);
        return;
    }
    i -= NB;
    if (i < NI) { winj[i] = f2bf(Winj[i]); return; }
    i -= NI;
    if (i < NB) {    // interleaved [BRe;BIm]
        int n = i / 768, k = i - n * 768;
        wb[i] = f2bf(Bp[(size_t)(n >> 1) * 1536 + k * 2 + (n & 1)]);
        return;
    }
    i -= NB;
    if (i < NB) {    // col-interleaved [CRe|-CIm] == sign-flipped natural Cp
        wc[i] = f2bf((i & 1) ? -Cp[i] : Cp[i]);
    }
}

// inputs -> hi/lo split buffers
__global__ __launch_bounds__(256) void split_convert_kernel(
    const float* __restrict__ in, unsigned short* __restrict__ outh,
    unsigned short* __restrict__ outl, int n4)
{
    int i = blockIdx.x * 256 + threadIdx.x;
    if (i >= n4) return;
    float4 a = ((const float4*)in)[i];
    ushort4 h, l;
    split_bf(a.x, h.x, l.x); split_bf(a.y, h.y, l.y);
    split_bf(a.z, h.z, l.z); split_bf(a.w, h.w, l.w);
    ((ushort4*)outh)[i] = h;
    ((ushort4*)outl)[i] = l;
}

// ---------------------------------------------------------------------------
// SPLIT-PRECISION bf16 MFMA GEMM: C = (Ah+Al) @ (Wh+Wl)^T  (3 MFMAs/k-step)
// grid = (N/128, M/128), XCD-swizzled.
// SMODE 0: fp32 out. SMODE 1: +bias, silu, fp32 out.
// ---------------------------------------------------------------------------
template <int SMODE>
__global__ __launch_bounds__(256) void mfma_gemm_split(
    const unsigned short* __restrict__ Ah, const unsigned short* __restrict__ Al,
    const unsigned short* __restrict__ Wh, const unsigned short* __restrict__ Wl,
    float* __restrict__ Cout, int N, const float* __restrict__ bias)
{
    constexpr int K = 768;
    __shared__ unsigned short lsAh[128 * 32];
    __shared__ unsigned short lsAl[128 * 32];
    __shared__ unsigned short lsBh[128 * 32];
    __shared__ unsigned short lsBl[128 * 32];
    const int tid  = threadIdx.x;
    const int wave = tid >> 6, lane = tid & 63;
    const int wm = wave >> 1, wn = wave & 1;
    int bx = blockIdx.x, by = blockIdx.y;
    xcd_swizzle(bx, by);
    const int row0 = by * 128, col0 = bx * 128;

    const int srow = (wave << 4) + (lane >> 2);    // 0..63
    const int scol = (lane & 3) << 3;              // 0,8,16,24
    const size_t ga0 = (size_t)(row0 + srow) * K + scol;
    const size_t ga1 = (size_t)(row0 + 64 + srow) * K + scol;
    const size_t gb0 = (size_t)(col0 + srow) * K + scol;
    const size_t gb1 = (size_t)(col0 + 64 + srow) * K + scol;
    const int l0 = srow * 32 + scol;
    const int l1 = (64 + srow) * 32 + scol;

    f32x4 acc[4][4];
#pragma unroll
    for (int i = 0; i < 4; ++i)
#pragma unroll
        for (int j = 0; j < 4; ++j) acc[i][j] = (f32x4){0.f, 0.f, 0.f, 0.f};

    const int rfo = ((lane & 15) * 32) + ((lane >> 4) << 3);

    for (int kt = 0; kt < K; kt += 32) {
        __syncthreads();
        gll16(Ah + ga0 + kt, &lsAh[l0]);
        gll16(Ah + ga1 + kt, &lsAh[l1]);
        gll16(Al + ga0 + kt, &lsAl[l0]);
        gll16(Al + ga1 + kt, &lsAl[l1]);
        gll16(Wh + gb0 + kt, &lsBh[l0]);
        gll16(Wh + gb1 + kt, &lsBh[l1]);
        gll16(Wl + gb0 + kt, &lsBl[l0]);
        gll16(Wl + gb1 + kt, &lsBl[l1]);
        __syncthreads();
        bf16x8 afh[4], afl[4], bfh[4], bfl[4];
#pragma unroll
        for (int i = 0; i < 4; ++i) {
            afh[i] = *(const bf16x8*)&lsAh[(wm * 64 + i * 16) * 32 + rfo];
            afl[i] = *(const bf16x8*)&lsAl[(wm * 64 + i * 16) * 32 + rfo];
        }
#pragma unroll
        for (int j = 0; j < 4; ++j) {
            bfh[j] = *(const bf16x8*)&lsBh[(wn * 64 + j * 16) * 32 + rfo];
            bfl[j] = *(const bf16x8*)&lsBl[(wn * 64 + j * 16) * 32 + rfo];
        }
#pragma unroll
        for (int i = 0; i < 4; ++i)
#pragma unroll
            for (int j = 0; j < 4; ++j) {
                acc[i][j] = __builtin_amdgcn_mfma_f32_16x16x32_bf16(afh[i], bfh[j], acc[i][j], 0, 0, 0);
                acc[i][j] = __builtin_amdgcn_mfma_f32_16x16x32_bf16(afh[i], bfl[j], acc[i][j], 0, 0, 0);
                acc[i][j] = __builtin_amdgcn_mfma_f32_16x16x32_bf16(afl[i], bfh[j], acc[i][j], 0, 0, 0);
            }
    }

    const int rbase = row0 + wm * 64 + ((lane >> 4) << 2);
    const int cbase = col0 + wn * 64 + (lane & 15);
#pragma unroll
    for (int i = 0; i < 4; ++i) {
#pragma unroll
        for (int j = 0; j < 4; ++j) {
            const int cg = cbase + j * 16;
            float bv = (SMODE == 1) ? bias[cg] : 0.f;
#pragma unroll
            for (int q = 0; q < 4; ++q) {
                const int rg = rbase + i * 16 + q;
                const size_t off = (size_t)rg * N + cg;
                float v = acc[i][j][q];
                if (SMODE == 1) {
                    float x = v + bv;
                    Cout[off] = x * sigmoid_fast(x);
                } else {
                    Cout[off] = v;
                }
            }
        }
    }
}

// ---------------------------------------------------------------------------
// plain bf16 MFMA GEMM. grid = (N/128, M/128), XCD-swizzled.
// MODE 2: +bf2f(resid)*Dv, fp32 out.  MODE 3: bf16 out, no epilogue.
// ---------------------------------------------------------------------------
template <int MODE>
__global__ __launch_bounds__(256) void mfma_gemm(
    const unsigned short* __restrict__ A, const unsigned short* __restrict__ W,
    void* __restrict__ Cout, int N,
    const unsigned short* __restrict__ resid, const float* __restrict__ Dv)
{
    constexpr int K = 768;
    __shared__ unsigned short lsA[128 * 32];
    __shared__ unsigned short lsB[128 * 32];
    const int tid  = threadIdx.x;
    const int wave = tid >> 6, lane = tid & 63;
    const int wm = wave >> 1, wn = wave & 1;
    int bx = blockIdx.x, by = blockIdx.y;
    xcd_swizzle(bx, by);
    const int row0 = by * 128, col0 = bx * 128;

    const int srow = (wave << 4) + (lane >> 2);
    const int scol = (lane & 3) << 3;
    const size_t ga0 = (size_t)(row0 + srow) * K + scol;
    const size_t ga1 = (size_t)(row0 + 64 + srow) * K + scol;
    const size_t gb0 = (size_t)(col0 + srow) * K + scol;
    const size_t gb1 = (size_t)(col0 + 64 + srow) * K + scol;
    const int l0 = srow * 32 + scol;
    const int l1 = (64 + srow) * 32 + scol;

    f32x4 acc[4][4];
#pragma unroll
    for (int i = 0; i < 4; ++i)
#pragma unroll
        for (int j = 0; j < 4; ++j) acc[i][j] = (f32x4){0.f, 0.f, 0.f, 0.f};

    const int rfo = ((lane & 15) * 32) + ((lane >> 4) << 3);

    for (int kt = 0; kt < K; kt += 32) {
        __syncthreads();
        gll16(A + ga0 + kt, &lsA[l0]);
        gll16(A + ga1 + kt, &lsA[l1]);
        gll16(W + gb0 + kt, &lsB[l0]);
        gll16(W + gb1 + kt, &lsB[l1]);
        __syncthreads();
        bf16x8 af[4], bfg[4];
#pragma unroll
        for (int i = 0; i < 4; ++i)
            af[i] = *(const bf16x8*)&lsA[(wm * 64 + i * 16) * 32 + rfo];
#pragma unroll
        for (int j = 0; j < 4; ++j)
            bfg[j] = *(const bf16x8*)&lsB[(wn * 64 + j * 16) * 32 + rfo];
#pragma unroll
        for (int i = 0; i < 4; ++i)
#pragma unroll
            for (int j = 0; j < 4; ++j)
                acc[i][j] = __builtin_amdgcn_mfma_f32_16x16x32_bf16(af[i], bfg[j], acc[i][j], 0, 0, 0);
    }

    const int rbase = row0 + wm * 64 + ((lane >> 4) << 2);
    const int cbase = col0 + wn * 64 + (lane & 15);
#pragma unroll
    for (int i = 0; i < 4; ++i) {
#pragma unroll
        for (int j = 0; j < 4; ++j) {
            const int cg = cbase + j * 16;
            const float dv = (MODE == 2) ? Dv[cg] : 0.f;
#pragma unroll
            for (int q = 0; q < 4; ++q) {
                const int rg = rbase + i * 16 + q;
                const size_t off = (size_t)rg * N + cg;
                float v = acc[i][j][q];
                if (MODE == 2) {
                    ((float*)Cout)[off] = v + bf2f(resid[off]) * dv;
                } else {
                    ((unsigned short*)Cout)[off] = f2bf(v);
                }
            }
        }
    }
}

// ---------------------------------------------------------------------------
// Causal depthwise conv (K=4) + bias + silu, ROLLING WINDOW.
// Each thread: one channel h, CRUN consecutive l. Each f1 element read once.
// ---------------------------------------------------------------------------
__global__ __launch_bounds__(256) void conv_silu_kernel(
    const float* __restrict__ x, const float* __restrict__ w,
    const float* __restrict__ cb, unsigned short* __restrict__ yh,
    unsigned short* __restrict__ yl)
{
    const int NRUN = MM / CRUN;                 // 1024
    int tid = blockIdx.x * 256 + threadIdx.x;   // over HH * NRUN
    if (tid >= HH * NRUN) return;
    const int h   = tid % HH;
    const int run = tid / HH;
    const int ml0 = run * CRUN;                 // global row start
    const int l0  = ml0 % LL;                   // within-sequence start
    const float w0 = w[h * KK + 0], w1 = w[h * KK + 1];
    const float w2 = w[h * KK + 2], w3 = w[h * KK + 3];
    const float bias = cb[h];
    float x0, x1, x2;                           // window: x[l-3], x[l-2], x[l-1]
    if (l0 == 0) {
        x0 = 0.f; x1 = 0.f; x2 = 0.f;
    } else {
        x0 = x[(size_t)(ml0 - 3) * HH + h];
        x1 = x[(size_t)(ml0 - 2) * HH + h];
        x2 = x[(size_t)(ml0 - 1) * HH + h];
    }
    for (int i = 0; i < CRUN; ++i) {
        const size_t m = (size_t)(ml0 + i);
        const float x3 = x[m * HH + h];
        float acc = bias;
        acc = fmaf(x0, w0, acc);
        acc = fmaf(x1, w1, acc);
        acc = fmaf(x2, w2, acc);
        acc = fmaf(x3, w3, acc);
        const float y = acc * sigmoid_fast(acc);
        unsigned short hi, lo;
        split_bf(y, hi, lo);
        yh[m * HH + h] = hi;
        yl[m * HH + h] = lo;
        x0 = x1; x1 = x2; x2 = x3;
    }
}

// ---------------------------------------------------------------------------
// Chunked scan, pass 1: per-(channel,chunk) local scan FROM ZERO.
// Writes: local states (bf16, to states buffer), per-step correction row
// [m10|m11] of cumulative T (packed 2xbf16 -> corr), and fp32 summaries.
// True state recovered later: x[m] = x_local[m] + m10(m)*z_start + m11(m)*x_start.
// ---------------------------------------------------------------------------
__global__ __launch_bounds__(256) void scan_chunk_kernel(
    const float* __restrict__ heads_rt, const unsigned short* __restrict__ heads_inj,
    const unsigned short* __restrict__ bu,
    const float* __restrict__ r_base, const float* __restrict__ th_base,
    const float* __restrict__ dt_base, const float* __restrict__ inj,
    unsigned short* __restrict__ states, unsigned int* __restrict__ corr,
    float4* __restrict__ summA, float4* __restrict__ summB)
{
    int g = blockIdx.x * 256 + threadIdx.x;
    if (g >= NC * NCH) return;
    int t = g % NCH;
    int j = g / NCH;
    int b = t / PP, p = t - b * PP;
    const float rb = r_base[p], tb = th_base[p], il = inj[p];
    const float dt = 0.02f + 0.98f * sigmoid_fast(dt_base[p]);
    float m00 = 1.f, m01 = 0.f, m10 = 0.f, m11 = 1.f;
    float vzR = 0.f, vxR = 0.f, vzI = 0.f, vxI = 0.f;
    const int mbase = b * LL + j * CLEN;
    for (int l = 0; l < CLEN; ++l) {
        const size_t m = (size_t)(mbase + l);
        const float2 rt = *(const float2*)(heads_rt + m * 768 + 2 * p);
        const float Ip = bf2f(heads_inj[m * 384 + p]);
        const ushort2 bv = *(const ushort2*)(bu + m * 768 + 2 * p);
        const float b0 = bf2f(bv.x), b1 = bf2f(bv.y);
        float c0, c1, gdt;
        step_coef(rt.x, rt.y, Ip, rb, tb, il, dt, c0, c1, gdt);
        const float azR = gdt * b0, azI = gdt * b1;
        float nm00 = c0 * m00 - c1 * m10;
        float nm01 = c0 * m01 - c1 * m11;
        m10 = fmaf(dt, nm00, m10);
        m11 = fmaf(dt, nm01, m11);
        m00 = nm00; m01 = nm01;
        float nvzR = c0 * vzR - c1 * vxR + azR;
        vxR = fmaf(dt, nvzR, vxR); vzR = nvzR;
        float nvzI = c0 * vzI - c1 * vxI + azI;
        vxI = fmaf(dt, nvzI, vxI); vzI = nvzI;
        // local state out (bf16) + correction row (2xbf16 packed)
        ushort2 sv;
        sv.x = f2bf(vxR);
        sv.y = f2bf(vxI);
        *(ushort2*)(states + m * 768 + 2 * p) = sv;
        corr[m * 384 + p] = ((unsigned int)f2bf(m11) << 16) | (unsigned int)f2bf(m10);
    }
    summA[g] = make_float4(m00, m01, m10, m11);
    summB[g] = make_float4(vzR, vxR, vzI, vxI);
}

// ---------------------------------------------------------------------------
// Pass 2: sequential scan over NC chunk summaries per channel -> chunk starts.
// ---------------------------------------------------------------------------
__global__ __launch_bounds__(256) void scan_mid_kernel(
    const float4* __restrict__ summA, const float4* __restrict__ summB,
    float4* __restrict__ starts)
{
    int t = blockIdx.x * 256 + threadIdx.x;
    if (t >= NCH) return;
    float zR = 0.f, xR = 0.f, zI = 0.f, xI = 0.f;
    for (int j = 0; j < NC; ++j) {
        starts[j * NCH + t] = make_float4(zR, xR, zI, xI);
        float4 Mv = summA[j * NCH + t];
        float4 Vv = summB[j * NCH + t];
        float nzR = Mv.x * zR + Mv.y * xR + Vv.x;
        float nxR = Mv.z * zR + Mv.w * xR + Vv.y;
        float nzI = Mv.x * zI + Mv.y * xI + Vv.z;
        float nxI = Mv.z * zI + Mv.w * xI + Vv.w;
        zR = nzR; xR = nxR; zI = nzI; xI = nxI;
    }
}

// ---------------------------------------------------------------------------
// Pass 3: elementwise correction — x += [m10 m11]·start. 2 p-pairs/thread.
// In-place on states (read-modify-write per element, no cross-thread deps).
// ---------------------------------------------------------------------------
__global__ __launch_bounds__(256) void scan_corr_kernel(
    const float4* __restrict__ starts, const unsigned int* __restrict__ corr,
    unsigned short* __restrict__ states)
{
    const int PH = PP / 2;                       // 192 pair-groups
    int i = blockIdx.x * 256 + threadIdx.x;      // over MM * PH
    if (i >= MM * PH) return;
    const int ph = i % PH;
    const int m  = i / PH;
    const int b  = m / LL;
    const int j  = (m % LL) / CLEN;
    const int p0 = ph * 2;
    const int t0 = b * PP + p0;
    float4 s0 = starts[(size_t)j * NCH + t0];
    float4 s1 = starts[(size_t)j * NCH + t0 + 1];
    uint2 cw = *(const uint2*)(corr + (size_t)m * 384 + p0);
    const float a10 = bf2f((unsigned short)(cw.x & 0xffff));
    const float a11 = bf2f((unsigned short)(cw.x >> 16));
    const float b10 = bf2f((unsigned short)(cw.y & 0xffff));
    const float b11 = bf2f((unsigned short)(cw.y >> 16));
    ushort4 sv = *(ushort4*)(states + (size_t)m * 768 + 2 * p0);
    float xR0 = bf2f(sv.x) + a10 * s0.x + a11 * s0.y;
    float xI0 = bf2f(sv.y) + a10 * s0.z + a11 * s0.w;
    float xR1 = bf2f(sv.z) + b10 * s1.x + b11 * s1.y;
    float xI1 = bf2f(sv.w) + b10 * s1.z + b11 * s1.w;
    sv.x = f2bf(xR0); sv.y = f2bf(xI0);
    sv.z = f2bf(xR1); sv.w = f2bf(xI1);
    *(ushort4*)(states + (size_t)m * 768 + 2 * p0) = sv;
}

// ---------------------------------------------------------------------------
extern "C" void kernel_launch(void* const* d_in, const int* in_sizes, int n_in,
                              void* d_out, int out_size, void* d_ws, size_t ws_size,
                              hipStream_t stream)
{
    const float* inputs  = (const float*)d_in[0];
    const float* Wl      = (const float*)d_in[1];
    const float* bl      = (const float*)d_in[2];
    const float* conv_w  = (const float*)d_in[3];
    const float* conv_b  = (const float*)d_in[4];
    const float* Wr      = (const float*)d_in[5];
    const float* Wth     = (const float*)d_in[6];
    const float* Winj    = (const float*)d_in[7];
    const float* r_base  = (const float*)d_in[8];
    const float* th_base = (const float*)d_in[9];
    const float* dt_base = (const float*)d_in[10];
    const float* inj_l   = (const float*)d_in[11];
    const float* Bp      = (const float*)d_in[12];
    const float* Cp      = (const float*)d_in[13];
    const float* Dv      = (const float*)d_in[14];
    float* out = (float*)d_out;

    // ---- workspace layout (lifetime-aliased) ----
    const size_t NB = 768 * 768, NI = 384 * 768, NMH = (size_t)MM * 768;
    unsigned short* wlh    = (unsigned short*)d_ws;
    unsigned short* wll    = wlh + NB;
    unsigned short* wrth_h = wll + NB;
    unsigned short* wrth_l = wrth_h + NB;
    unsigned short* winj   = wrth_l + NB;
    unsigned short* wb     = winj + NI;
    unsigned short* wc     = wb + NB;
    unsigned short* inh    = wc + NB;            // MM*768 bf16, live t3..t9
    unsigned short* inl    = inh + NMH;          // live t3 only -> states later
    unsigned short* f2h    = inl + NMH;          // conv out hi, live t4..t5 -> corr later
    unsigned short* f2l    = f2h + NMH;          // conv out lo
    unsigned short* hinj   = f2l + NMH;          // heads_inj bf16 MM*384
    float* f1       = (float*)(hinj + (size_t)MM * 384);   // enc out fp32 (96MB)
    float* heads_rt = f1;                        // overlays f1 (dead after conv)
    float4* summA = (float4*)(f1 + NMH);         // NC*NCH
    float4* summB = summA + (size_t)NC * NCH;
    float4* starts= summB + (size_t)NC * NCH;
    unsigned short* bu = (unsigned short*)d_out; // bf16 MM*768, dead after scan
    unsigned short* states = inl;                // overlays dead inl
    unsigned int* corr = (unsigned int*)f2h;     // overlays f2h (dead after t5b)

    // t1. repack weights ; t2. split-convert inputs
    {
        int total = (int)(4 * NB + NI);
        repack_kernel<<<(total + 255) / 256, 256, 0, stream>>>(
            Wl, Wr, Wth, Winj, Bp, Cp, wlh, wll, wrth_h, wrth_l, winj, wb, wc);
        int n4 = (int)(NMH / 4);
        split_convert_kernel<<<(n4 + 255) / 256, 256, 0, stream>>>(inputs, inh, inl, n4);
    }
    // t3. encoder (split): f1 = silu(inputs @ Wl^T + bl)  [fp32]
    mfma_gemm_split<1><<<dim3(6, MM / 128), 256, 0, stream>>>(
        inh, inl, wlh, wll, f1, 768, bl);
    // t4. conv + silu (rolling window): f1 -> f2 hi/lo
    {
        int nthr = HH * (MM / CRUN);
        conv_silu_kernel<<<(nthr + 255) / 256, 256, 0, stream>>>(f1, conv_w, conv_b, f2h, f2l);
    }
    // t5a. R/Th heads (split, interleaved rows): heads_rt [fp32, overlays f1]
    mfma_gemm_split<0><<<dim3(6, MM / 128), 256, 0, stream>>>(
        f2h, f2l, wrth_h, wrth_l, heads_rt, 768, nullptr);
    // t5b. Inj head (plain): hinj = f2h @ Winj^T  [bf16]
    mfma_gemm<3><<<dim3(3, MM / 128), 256, 0, stream>>>(
        f2h, winj, (void*)hinj, 384, nullptr, nullptr);
    // t6. input projection (plain, interleaved rows): bu [bf16, in d_out]
    mfma_gemm<3><<<dim3(6, MM / 128), 256, 0, stream>>>(
        inh, wb, (void*)bu, 768, nullptr, nullptr);
    // t7. chunked scan: local pass (writes states_local + corr) -> mid -> correction
    scan_chunk_kernel<<<(NC * NCH) / 256, 256, 0, stream>>>(
        heads_rt, hinj, bu, r_base, th_base, dt_base, inj_l,
        states, corr, summA, summB);
    scan_mid_kernel<<<(NCH + 255) / 256, 256, 0, stream>>>(summA, summB, starts);
    {
        int nthr = MM * (PP / 2);
        scan_corr_kernel<<<(nthr + 255) / 256, 256, 0, stream>>>(starts, corr, states);
    }
    // t9. output projection + residual (resid read as bf16 inh)
    mfma_gemm<2><<<dim3(6, MM / 128), 256, 0, stream>>>(
        states, wc, (void*)out, 768, inh, Dv);
}